// Round 14
// baseline (131.909 us; speedup 1.0000x reference)
//
#include <hip/hip_runtime.h>
#include <hip/hip_bf16.h>
#include <hip/hip_fp16.h>
#include <math.h>

#define BB   4
#define LL   4096
#define CCH  256
#define KK   7
#define HIDN 32
#define MTOT (BB * LL)          // 16384 rows
#define NOFF (CCH * KK)         // 1792
#define NP   4096               // padded fused N: col = g*16 + idx (0..6 off, 7 pad, 8..14 mask, 15 pad)
#define NBLK ((NP / 128) * (MTOT / 128))   // 4096 fused blocks
#define NDWB 4096               // dwconv blocks
#define NPREPB 672              // prep blocks (6 tasks x 112)

#define LOG2E  1.4426950408889634f
#define NLOG2E2 (-2.8853900817779268f)   // -2*log2(e)
#define LN2    0.6931471805599453f

typedef __attribute__((ext_vector_type(8))) short short8;
typedef __attribute__((ext_vector_type(4))) short short4v;
typedef __attribute__((ext_vector_type(4))) float f32x4;
typedef __attribute__((ext_vector_type(2))) __fp16 fp16x2;
typedef __attribute__((address_space(1))) void gvoid_t;
typedef __attribute__((address_space(3))) void svoid_t;

__device__ __forceinline__ float siluf(float v) { return v / (1.0f + expf(-v)); }
__device__ __forceinline__ float bf2f(ushort u) { unsigned x = (unsigned)u << 16; return __uint_as_float(x); }
__device__ __forceinline__ float h2f(ushort u) { __half_raw hr; hr.x = u; return __half2float(__half(hr)); }
__device__ __forceinline__ float rcpf(float x) { return __builtin_amdgcn_rcpf(x); }
__device__ __forceinline__ unsigned pkh(float a, float b) {
    union { fp16x2 h; unsigned u; } cv;
    cv.h = __builtin_amdgcn_cvt_pkrtz(a, b);
    return cv.u;
}
__device__ __forceinline__ void compute_env(const float* raw_sigma, float* ev) {
    float sp = log1pf(expf(raw_sigma[0]));
    sp = fminf(fmaxf(sp, 0.05f), 0.5f);
    float sg = fmaxf(sp, 1e-6f);
    float ssum = 0.0f;
    for (int k = 0; k < KK; ++k) {
        float gk = -0.5f + (float)k * (1.0f / 6.0f);
        float d = gk / sg;
        ev[k] = expf(-0.5f * d * d);
        ssum += ev[k];
    }
    ssum = fmaxf(ssum, 1e-8f);
    for (int k = 0; k < KK; ++k) ev[k] /= ssum;
}

// ============ merged pre-work: dwconv+xbf | weight transposes | kernel-net precompute ============
__global__ __launch_bounds__(256) void pre_kernel(
    const float* __restrict__ x, const float* __restrict__ dw1_w, const float* __restrict__ dw1_b,
    const float* __restrict__ w_in, const float* __restrict__ dw2_w, const float* __restrict__ w_out,
    const float* __restrict__ w_off, const float* __restrict__ w_mask,
    const float* __restrict__ raw_sigma,
    const float* __restrict__ k0w, const float* __restrict__ k0b,
    const float* __restrict__ k1w, const float* __restrict__ k1b,
    const float* __restrict__ k2w, const float* __restrict__ k2b,
    const float* __restrict__ k3w, const float* __restrict__ k3b,
    const float* __restrict__ b_off, const float* __restrict__ b_mask,
    __hip_bfloat16* __restrict__ xbf, __hip_bfloat16* __restrict__ hbf,
    __hip_bfloat16* __restrict__ wtin, __hip_bfloat16* __restrict__ wtdw2,
    __hip_bfloat16* __restrict__ wtout, __hip_bfloat16* __restrict__ wtcomb,
    float* __restrict__ kws2, float* __restrict__ bcomb)
{
    const int bid = blockIdx.x;
    const int tid = threadIdx.x;
    __shared__ float t[64][65];
    __shared__ float envs_sh[8];
    __shared__ float h0[KK][HIDN];
    __shared__ float h1[KK][HIDN];
    __shared__ float h2[KK][HIDN];
    __shared__ float flatw[NOFF];

    if (bid < NDWB) {
        size_t base = ((size_t)bid * 256 + tid) * 4;
        int c = (int)(base & (CCH - 1));
        int l = (int)((base >> 8) & (LL - 1));
        float4 xm = *(const float4*)&x[base];
        float4 xl = make_float4(0.f, 0.f, 0.f, 0.f);
        float4 xr = make_float4(0.f, 0.f, 0.f, 0.f);
        if (l > 0)      xl = *(const float4*)&x[base - CCH];
        if (l < LL - 1) xr = *(const float4*)&x[base + CCH];
        float vm[4] = {xm.x, xm.y, xm.z, xm.w};
        float vl[4] = {xl.x, xl.y, xl.z, xl.w};
        float vr[4] = {xr.x, xr.y, xr.z, xr.w};
        ushort xo[4], ho[4];
        #pragma unroll
        for (int j = 0; j < 4; ++j) {
            int cc = c + j;
            float s = vm[j] * dw1_w[cc * 3 + 1] + vl[j] * dw1_w[cc * 3 + 0]
                    + vr[j] * dw1_w[cc * 3 + 2] + dw1_b[cc];
            __hip_bfloat16 hb = __float2bfloat16(siluf(s));
            __hip_bfloat16 xb = __float2bfloat16(vm[j]);
            ho[j] = *(ushort*)&hb;
            xo[j] = *(ushort*)&xb;
        }
        *(short4v*)&xbf[base] = *(short4v*)xo;
        *(short4v*)&hbf[base] = *(short4v*)ho;
        return;
    }
    if (bid < NDWB + NPREPB) {
        const int task = (bid - NDWB) / 112;
        const int bx = (bid - NDWB) % 112;
        if (task == 5) {
            if (bx >= 64) return;
            unsigned u = bx * 256 + tid;
            unsigned row_sel = u >> 5, chunk = u & 31;
            unsigned g = row_sel >> 1, which = row_sel & 1;
            unsigned row = g * 16 + 7 + which * 8;
            short8 z = {};
            *(short8*)((ushort*)wtcomb + (size_t)row * 256 + chunk * 8) = z;
            return;
        }
        const float* src; __hip_bfloat16* dst; int N; int mode = 0;
        switch (task) {
            case 0: src = w_in;  dst = wtin;  N = 256;  break;
            case 1: src = dw2_w; dst = wtdw2; N = 256;  break;
            case 2: src = w_out; dst = wtout; N = 256;  break;
            case 3: src = w_off;  dst = wtcomb; N = NOFF; mode = 1; break;
            default: src = w_mask; dst = wtcomb; N = NOFF; mode = 2; break;
        }
        int ntiles = 4 * (N / 64);
        if (bx >= ntiles) return;
        if (mode == 2 && tid == 0) compute_env(raw_sigma, envs_sh);
        int tk = (bx & 3) * 64;
        int tn = (bx >> 2) * 64;
        #pragma unroll
        for (int i = 0; i < 16; ++i) {
            int e = i * 256 + tid, kk = e >> 6, nn = e & 63;
            t[kk][nn] = src[(size_t)(tk + kk) * N + tn + nn];
        }
        __syncthreads();
        #pragma unroll
        for (int i = 0; i < 16; ++i) {
            int e = i * 256 + tid, nn = e >> 6, kk = e & 63;
            int c = tn + nn;
            float v = t[kk][nn];
            int cp;
            if (mode == 0) cp = c;
            else {
                int g = c / KK, k = c % KK;
                if (mode == 1) { cp = g * 16 + k;     v *= NLOG2E2; }
                else           { cp = g * 16 + 8 + k; v *= envs_sh[k] * LOG2E; }
            }
            dst[(size_t)cp * 256 + tk + kk] = __float2bfloat16(v);
        }
        return;
    }
    {
        int tt = tid;
        if (tt < KK * HIDN) {
            int k = tt / HIDN, j = tt % HIDN;
            float gk = -0.5f + (float)k * (1.0f / 6.0f);
            float v = gk * 30.0f * k0w[j] + k0b[j];
            h0[k][j] = siluf(v);
        }
        __syncthreads();
        if (tt < KK * HIDN) {
            int k = tt / HIDN, j = tt % HIDN;
            float s = k1b[j];
            #pragma unroll
            for (int i = 0; i < HIDN; ++i) s += h0[k][i] * k1w[i * HIDN + j];
            h1[k][j] = siluf(s);
        }
        __syncthreads();
        if (tt < KK * HIDN) {
            int k = tt / HIDN, j = tt % HIDN;
            float s = k2b[j];
            #pragma unroll
            for (int i = 0; i < HIDN; ++i) s += h1[k][i] * k2w[i * HIDN + j];
            h2[k][j] = siluf(s);
        }
        __syncthreads();
        for (int k = 0; k < KK; ++k) {
            float s = k3b[tt];
            #pragma unroll
            for (int i = 0; i < HIDN; ++i) s += h2[k][i] * k3w[i * CCH + tt];
            flatw[k * CCH + tt] = s;
        }
        if (tt == 0) compute_env(raw_sigma, envs_sh);
        __syncthreads();
        #pragma unroll
        for (int k = 0; k < KK; ++k) kws2[tt * 8 + k] = flatw[tt * KK + k];
        kws2[tt * 8 + 7] = 0.0f;
        #pragma unroll
        for (int k = 0; k < KK; ++k) {
            bcomb[tt * 16 + k]     = b_off[tt * KK + k] * NLOG2E2;
            bcomb[tt * 16 + 8 + k] = b_mask[tt * KK + k] * envs_sh[k] * LOG2E;
        }
        bcomb[tt * 16 + 7]  = 0.0f;
        bcomb[tt * 16 + 15] = 0.0f;
    }
}

// ---------------- shared GEMM core (LDS-staged, r11-verified) ----------------
template<int OUTBF>
__device__ __forceinline__ void gemm_core(
    const __hip_bfloat16* __restrict__ A, const __hip_bfloat16* __restrict__ Bt,
    const float* __restrict__ bias, void* __restrict__ C, int N, char* lds,
    int bx, int by)
{
    char* As = lds;
    char* Bs = lds + 16384;
    const int tid = threadIdx.x, lane = tid & 63, w = tid >> 6;
    const int wr = w >> 1, wc = w & 1;
    const size_t m0 = (size_t)by * 128, n0 = (size_t)bx * 128;

    const int srow = w * 32 + (lane >> 3);
    const int sgr  = (lane & 7) ^ ((lane >> 3) & 7);
    const __hip_bfloat16* a_src = A  + (m0 + srow) * 256 + sgr * 8;
    const __hip_bfloat16* b_src = Bt + (n0 + srow) * 256 + sgr * 8;
    char* a_dst = As + (w * 32) * 128;
    char* b_dst = Bs + (w * 32) * 128;

    f32x4 acc[4][4] = {};

    for (int kt = 0; kt < 4; ++kt) {
        const int k0 = kt * 64;
        #pragma unroll
        for (int inst = 0; inst < 4; ++inst) {
            __builtin_amdgcn_global_load_lds((gvoid_t*)(a_src + k0 + (size_t)inst * 8 * 256),
                                             (svoid_t*)(a_dst + inst * 1024), 16, 0, 0);
            __builtin_amdgcn_global_load_lds((gvoid_t*)(b_src + k0 + (size_t)inst * 8 * 256),
                                             (svoid_t*)(b_dst + inst * 1024), 16, 0, 0);
        }
        __syncthreads();
        #pragma unroll
        for (int ks = 0; ks < 2; ++ks) {
            short8 a[4], b[4];
            #pragma unroll
            for (int i = 0; i < 4; ++i) {
                int mr = wr * 64 + i * 16 + (lane & 15);
                int gk = ks * 4 + (lane >> 4);
                a[i] = *(const short8*)(As + mr * 128 + ((gk ^ (mr & 7)) << 4));
                int nr = wc * 64 + i * 16 + (lane & 15);
                b[i] = *(const short8*)(Bs + nr * 128 + ((gk ^ (nr & 7)) << 4));
            }
            #pragma unroll
            for (int i = 0; i < 4; ++i)
                #pragma unroll
                for (int j = 0; j < 4; ++j)
                    acc[i][j] = __builtin_amdgcn_mfma_f32_16x16x32_bf16(a[i], b[j], acc[i][j], 0, 0, 0);
        }
        __syncthreads();
    }
    #pragma unroll
    for (int j = 0; j < 4; ++j) {
        int col = (int)n0 + wc * 64 + j * 16 + (lane & 15);
        float bb = bias[col];
        #pragma unroll
        for (int i = 0; i < 4; ++i) {
            size_t row0 = m0 + wr * 64 + i * 16 + ((lane >> 4) << 2);
            f32x4 v = acc[i][j];
            #pragma unroll
            for (int q = 0; q < 4; ++q) {
                float val = v[q] + bb;
                if (OUTBF) ((__hip_bfloat16*)C)[(row0 + q) * N + col] = __float2bfloat16(val);
                else       ((float*)C)[(row0 + q) * N + col] = val;
            }
        }
    }
}

// dual small GEMM: z=0 -> x_proj, z=1 -> x_dw (independent, one dispatch)
__global__ __launch_bounds__(256) void gemm_dual_k256(
    const __hip_bfloat16* __restrict__ A0, const __hip_bfloat16* __restrict__ Bt0,
    const float* __restrict__ bias0, __hip_bfloat16* __restrict__ C0,
    const __hip_bfloat16* __restrict__ A1, const __hip_bfloat16* __restrict__ Bt1,
    const float* __restrict__ bias1, __hip_bfloat16* __restrict__ C1)
{
    __shared__ __align__(16) char lds[32768];
    if (blockIdx.z == 0) gemm_core<1>(A0, Bt0, bias0, C0, 256, lds, blockIdx.x, blockIdx.y);
    else                 gemm_core<1>(A1, Bt1, bias1, C1, 256, lds, blockIdx.x, blockIdx.y);
}

// out GEMM + finalize tail block (by==128)
__global__ __launch_bounds__(256) void gemm_out_k256(
    const __hip_bfloat16* __restrict__ A, const __hip_bfloat16* __restrict__ Bt,
    const float* __restrict__ bias, float* __restrict__ C,
    const float* __restrict__ partials, float* __restrict__ out_tail)
{
    __shared__ __align__(16) char lds[32768];
    if (blockIdx.y == 128) {
        if (blockIdx.x != 0) return;
        __shared__ float redr[256], rede[256];
        int t = threadIdx.x;
        float r = 0.0f, e = 0.0f;
        for (int i = t; i < NBLK; i += 256) {
            r += partials[2 * i];
            e += partials[2 * i + 1];
        }
        redr[t] = r; rede[t] = e;
        __syncthreads();
        for (int s = 128; s > 0; s >>= 1) {
            if (t < s) { redr[t] += redr[t + s]; rede[t] += rede[t + s]; }
            __syncthreads();
        }
        if (t == 0) {
            out_tail[0] = redr[0] / 29360128.0f;   // B*L*G*K
            out_tail[1] = rede[0] / 4194304.0f;    // B*L*G
        }
        return;
    }
    gemm_core<0>(A, Bt, bias, C, 256, lds, blockIdx.x, blockIdx.y);
}

// per-point epilogue body; CLAMP_STMT applied to p
#define EPI2_LOOP(CLAMP_STMT)                                                           \
    _Pragma("unroll")                                                                   \
    for (int pp = 0; pp < 4; ++pp) {                                                    \
        const int r = rb + 32 * pp;                                                     \
        short8 ca = *(const short8*)(lds + r * 256 + (((2 * gg) ^ (r & 15)) << 4));     \
        short8 cb = *(const short8*)(lds + r * 256 + (((2 * gg + 1) ^ (r & 15)) << 4)); \
        const int l = l0 + r;                                                           \
        float es = 0.0f, tacc = 0.0f, o = 0.0f;                                         \
        _Pragma("unroll")                                                               \
        for (int k = 0; k < KK; ++k) {                                                  \
            float mvk = h2f((ushort)cb[k]);        /* env-scaled logit, no max-sub */   \
            float e = exp2f(mvk);                                                       \
            es += e; tacc += e * mvk;                                                   \
            float zp = fminf(h2f((ushort)ca[k]), 80.f);   /* = -2z*log2e */             \
            float ee = exp2f(zp);                          /* = exp(-2z) */             \
            float ov = 2.0f * (1.0f - ee) * rcpf(1.0f + ee);   /* = 2*tanh(z) */        \
            reg_acc += ov * ov;                                                         \
            float p = (float)(l + k - 3) + ov;                                          \
            CLAMP_STMT;                                                                 \
            int pf = (int)p;                                                            \
            float wcf = p - (float)pf;                                                  \
            int ix = pf - (l0 - 5);                                                     \
            float sv = XsF[ix * 8 + gg] * (1.0f - wcf) + XsF[ix * 8 + 8 + gg] * wcf;    \
            o += sv * kwv[k] * e;                                                       \
        }                                                                               \
        float inv = rcpf(es);                                                           \
        ent_acc += tacc * inv - __log2f(es);                                            \
        out_pre[(m0 + r) * CCH + g0 + gg] = __float2bfloat16(o * inv);                  \
    }

// ---------------- fused off|mask GEMM + LDS-C-tile tanh/gather/softmax epilogue ----------------
// r11 structure: staged GEMM, XCD swizzle, Xs at top (now f32), single-chunk epilogue.
__global__ __launch_bounds__(256) void gemm_fused_sample(
    const __hip_bfloat16* __restrict__ A,      // xdw [16384][256]
    const __hip_bfloat16* __restrict__ Bt,     // wtcomb [4096][256] prescaled
    const float* __restrict__ bcomb,           // [4096] prescaled padded biases
    const __hip_bfloat16* __restrict__ xproj,  // [4][4096][256]
    const float* __restrict__ kws2,            // [256][8] kw, pad k=7 -> 0
    __hip_bfloat16* __restrict__ out_pre,
    float* __restrict__ partials)              // [NBLK][2]
{
    __shared__ __align__(16) char lds[37248];   // 32KB GEMM/Cs + 4.5KB Xs(f32)
    char* As = lds;
    char* Bs = lds + 16384;
    const int tid = threadIdx.x, lane = tid & 63, w = tid >> 6;
    const int wr = w >> 1, wc = w & 1;
    // XCD-aware bijective swizzle: each XCD gets 16 contiguous m-panels (A reuse in L2)
    const int flat = blockIdx.y * 32 + blockIdx.x;
    const int wid = ((flat & 7) << 9) | (flat >> 3);
    const int bx = wid & 31, by = wid >> 5;
    const size_t m0 = (size_t)by * 128;
    const int n0 = bx * 128, g0 = bx * 8;
    const int l0 = (int)(m0 & (LL - 1));
    const int bidx = (int)(m0 >> 12);

    // stage Xs as f32 (xproj rows l0-5..l0+134, 8 cols): reg load + convert + LDS write.
    // Completes before epilogue (covered by K-loop barriers).
    if (tid < 140) {
        int rr = min(max(l0 - 5 + tid, 0), LL - 1);
        short8 v = *(const short8*)((const ushort*)xproj + ((size_t)bidx * LL + rr) * CCH + g0);
        float4 f0, f1;
        f0.x = bf2f((ushort)v[0]); f0.y = bf2f((ushort)v[1]);
        f0.z = bf2f((ushort)v[2]); f0.w = bf2f((ushort)v[3]);
        f1.x = bf2f((ushort)v[4]); f1.y = bf2f((ushort)v[5]);
        f1.z = bf2f((ushort)v[6]); f1.w = bf2f((ushort)v[7]);
        float4* dst = (float4*)(lds + 32768) + tid * 2;
        dst[0] = f0;
        dst[1] = f1;
    }

    const int srow = w * 32 + (lane >> 3);
    const int sgr  = (lane & 7) ^ ((lane >> 3) & 7);
    const __hip_bfloat16* a_src = A  + (m0 + srow) * 256 + sgr * 8;
    const __hip_bfloat16* b_src = Bt + (size_t)(n0 + srow) * 256 + sgr * 8;
    char* a_dst = As + (w * 32) * 128;
    char* b_dst = Bs + (w * 32) * 128;

    f32x4 acc[4][4] = {};   // acc[j][i], operand-swapped

    for (int kt = 0; kt < 4; ++kt) {
        const int k0 = kt * 64;
        #pragma unroll
        for (int inst = 0; inst < 4; ++inst) {
            __builtin_amdgcn_global_load_lds((gvoid_t*)(a_src + k0 + (size_t)inst * 8 * 256),
                                             (svoid_t*)(a_dst + inst * 1024), 16, 0, 0);
            __builtin_amdgcn_global_load_lds((gvoid_t*)(b_src + k0 + (size_t)inst * 8 * 256),
                                             (svoid_t*)(b_dst + inst * 1024), 16, 0, 0);
        }
        __syncthreads();
        #pragma unroll
        for (int ks = 0; ks < 2; ++ks) {
            short8 a[4], b[4];
            #pragma unroll
            for (int i = 0; i < 4; ++i) {
                int mr = wr * 64 + i * 16 + (lane & 15);
                int gk = ks * 4 + (lane >> 4);
                a[i] = *(const short8*)(As + mr * 128 + ((gk ^ (mr & 7)) << 4));
                int nr = wc * 64 + i * 16 + (lane & 15);
                b[i] = *(const short8*)(Bs + nr * 128 + ((gk ^ (nr & 7)) << 4));
            }
            #pragma unroll
            for (int i = 0; i < 4; ++i)
                #pragma unroll
                for (int j = 0; j < 4; ++j)
                    acc[j][i] = __builtin_amdgcn_mfma_f32_16x16x32_bf16(b[j], a[i], acc[j][i], 0, 0, 0);
        }
        __syncthreads();
    }

    // ---- epilogue 1: bias + fp16 pack, b64 store into swizzled Cs (reuses As/Bs) ----
    {
        const int rl = lane & 15, grp = lane >> 4;
        #pragma unroll
        for (int j = 0; j < 4; ++j) {
            float4 bi = *(const float4*)&bcomb[n0 + wc * 64 + j * 16 + grp * 4];
            const int gran = wc * 8 + j * 2 + (grp >> 1);
            #pragma unroll
            for (int i = 0; i < 4; ++i) {
                f32x4 v = acc[j][i];
                uint2 pk;
                pk.x = pkh(v[0] + bi.x, v[1] + bi.y);
                pk.y = pkh(v[2] + bi.z, v[3] + bi.w);
                int row = wr * 64 + i * 16 + rl;
                int addr = row * 256 + ((gran ^ rl) << 4) + (grp & 1) * 8;
                *(uint2*)(lds + addr) = pk;
            }
        }
    }
    __syncthreads();

    // ---- epilogue 2: 4 points/thread ----
    const float* XsF = (const float*)(lds + 32768);
    const int gg = tid & 7, rb = tid >> 3;   // rb 0..31
    float kwv[KK];
    {
        const float* kp = &kws2[(size_t)(g0 + gg) * 8];
        float4 ka = *(const float4*)kp;
        float4 kb = *(const float4*)(kp + 4);
        kwv[0] = ka.x; kwv[1] = ka.y; kwv[2] = ka.z; kwv[3] = ka.w;
        kwv[4] = kb.x; kwv[5] = kb.y; kwv[6] = kb.z;
    }
    float reg_acc = 0.0f, ent_acc = 0.0f;
    const int lblk = by & 31;
    if (lblk != 0 && lblk != 31) {
        // interior: p in [l0-5, l0+133] automatically in-range, no clamps
        EPI2_LOOP(;)
    } else {
        EPI2_LOOP(p = fminf(fmaxf(p, 0.0f), 4095.0f))
    }

    // wave butterfly, then per-block partial via LDS (no atomics)
    #pragma unroll
    for (int d = 1; d < 64; d <<= 1) {
        reg_acc += __shfl_xor(reg_acc, d);
        ent_acc += __shfl_xor(ent_acc, d);
    }
    __syncthreads();                       // all Cs/Xs reads complete before LDS reuse
    float* redv = (float*)lds;
    if (lane == 0) { redv[w] = reg_acc; redv[4 + w] = ent_acc; }
    __syncthreads();
    if (tid == 0) {
        float r2 = redv[0] + redv[1] + redv[2] + redv[3];
        float e2 = redv[4] + redv[5] + redv[6] + redv[7];
        partials[wid * 2]     = r2;
        partials[wid * 2 + 1] = e2 * LN2;
    }
}

extern "C" void kernel_launch(void* const* d_in, const int* in_sizes, int n_in,
                              void* d_out, int out_size, void* d_ws, size_t ws_size,
                              hipStream_t stream)
{
    const float* x         = (const float*)d_in[0];
    const float* raw_sigma = (const float*)d_in[1];
    const float* w_in      = (const float*)d_in[2];
    const float* b_in      = (const float*)d_in[3];
    const float* w_out     = (const float*)d_in[4];
    const float* b_out     = (const float*)d_in[5];
    const float* dw1_w     = (const float*)d_in[6];
    const float* dw1_b     = (const float*)d_in[7];
    const float* dw2_w     = (const float*)d_in[8];
    const float* dw2_b     = (const float*)d_in[9];
    const float* w_off     = (const float*)d_in[10];
    const float* b_off     = (const float*)d_in[11];
    const float* w_mask    = (const float*)d_in[12];
    const float* b_mask    = (const float*)d_in[13];
    const float* k0w       = (const float*)d_in[14];
    const float* k0b       = (const float*)d_in[15];
    const float* k1w       = (const float*)d_in[16];
    const float* k1b       = (const float*)d_in[17];
    const float* k2w       = (const float*)d_in[18];
    const float* k2b       = (const float*)d_in[19];
    const float* k3w       = (const float*)d_in[20];
    const float* k3b       = (const float*)d_in[21];

    char* ws = (char*)d_ws;
    const size_t MB8 = (size_t)8 * 1024 * 1024;
    __hip_bfloat16* xbf    = (__hip_bfloat16*)(ws + 0);
    __hip_bfloat16* hbf    = (__hip_bfloat16*)(ws + MB8);        // h, reused as out_pre
    __hip_bfloat16* xdwbf  = (__hip_bfloat16*)(ws + 2 * MB8);
    __hip_bfloat16* xprojb = (__hip_bfloat16*)(ws + 3 * MB8);
    char* wbase = ws + 4 * MB8;
    __hip_bfloat16* wtin   = (__hip_bfloat16*)(wbase);                    // 128KB
    __hip_bfloat16* wtdw2  = (__hip_bfloat16*)(wbase + 131072);           // 128KB
    __hip_bfloat16* wtout  = (__hip_bfloat16*)(wbase + 262144);           // 128KB
    __hip_bfloat16* wtcomb = (__hip_bfloat16*)(wbase + 393216);           // 4096*256*2 = 2MB
    float* bcomb    = (float*)(wbase + 393216 + 2097152);                 // 4096 floats
    float* kws2     = bcomb + NP;                                         // 2048 floats
    float* partials = kws2 + 2048;                                        // 8192 floats

    // 1) merged pre-work: dwconv+xbf | weight transposes | kernel-net (one dispatch)
    pre_kernel<<<NDWB + NPREPB + 1, 256, 0, stream>>>(
        x, dw1_w, dw1_b, w_in, dw2_w, w_out, w_off, w_mask, raw_sigma,
        k0w, k0b, k1w, k1b, k2w, k2b, k3w, k3b, b_off, b_mask,
        xbf, hbf, wtin, wtdw2, wtout, wtcomb, kws2, bcomb);
    // 2) x_proj and x_dw in one dispatch
    gemm_dual_k256<<<dim3(2, 128, 2), 256, 0, stream>>>(xbf, wtin, b_in, xprojb,
                                                        hbf, wtdw2, dw2_b, xdwbf);
    // 3) fused off|mask GEMM + LDS-tile sampling/softmax  (out_pre -> hbf, partials out)
    gemm_fused_sample<<<dim3(NP / 128, MTOT / 128), 256, 0, stream>>>(
        xdwbf, wtcomb, bcomb, xprojb, kws2, hbf, partials);
    // 4) out = out_pre @ w_out + b_out (fp32) + finalize tail block
    gemm_out_k256<<<dim3(2, 129), 256, 0, stream>>>(hbf, wtout, b_out, (float*)d_out,
                                                    partials, (float*)d_out + (size_t)MTOT * CCH);
}

// Round 15
// 124.177 us; speedup vs baseline: 1.0623x; 1.0623x over previous
//
#include <hip/hip_runtime.h>
#include <hip/hip_bf16.h>
#include <hip/hip_fp16.h>
#include <math.h>

#define BB   4
#define LL   4096
#define CCH  256
#define KK   7
#define HIDN 32
#define MTOT (BB * LL)          // 16384 rows
#define NOFF (CCH * KK)         // 1792
#define NP   4096               // padded fused N: col = g*16 + idx (0..6 off, 7 pad, 8..14 mask, 15 pad)
#define NBLK ((NP / 128) * (MTOT / 128))   // 4096 fused blocks
#define NDWB 4096               // dwconv blocks
#define NPREPB 672              // prep blocks (6 tasks x 112)

#define LOG2E  1.4426950408889634f
#define NLOG2E2 (-2.8853900817779268f)   // -2*log2(e)
#define LN2    0.6931471805599453f

typedef __attribute__((ext_vector_type(8))) short short8;
typedef __attribute__((ext_vector_type(4))) short short4v;
typedef __attribute__((ext_vector_type(4))) float f32x4;
typedef __attribute__((ext_vector_type(2))) __fp16 fp16x2;
typedef __attribute__((address_space(1))) void gvoid_t;
typedef __attribute__((address_space(3))) void svoid_t;

__device__ __forceinline__ float siluf(float v) { return v / (1.0f + expf(-v)); }
__device__ __forceinline__ float bf2f(ushort u) { unsigned x = (unsigned)u << 16; return __uint_as_float(x); }
__device__ __forceinline__ float h2f(ushort u) { __half_raw hr; hr.x = u; return __half2float(__half(hr)); }
__device__ __forceinline__ float rcpf(float x) { return __builtin_amdgcn_rcpf(x); }
__device__ __forceinline__ unsigned pkh(float a, float b) {
    union { fp16x2 h; unsigned u; } cv;
    cv.h = __builtin_amdgcn_cvt_pkrtz(a, b);
    return cv.u;
}
__device__ __forceinline__ void compute_env(const float* raw_sigma, float* ev) {
    float sp = log1pf(expf(raw_sigma[0]));
    sp = fminf(fmaxf(sp, 0.05f), 0.5f);
    float sg = fmaxf(sp, 1e-6f);
    float ssum = 0.0f;
    for (int k = 0; k < KK; ++k) {
        float gk = -0.5f + (float)k * (1.0f / 6.0f);
        float d = gk / sg;
        ev[k] = expf(-0.5f * d * d);
        ssum += ev[k];
    }
    ssum = fmaxf(ssum, 1e-8f);
    for (int k = 0; k < KK; ++k) ev[k] /= ssum;
}

// ============ merged pre-work: dwconv+xbf | weight transposes | kernel-net precompute ============
__global__ __launch_bounds__(256) void pre_kernel(
    const float* __restrict__ x, const float* __restrict__ dw1_w, const float* __restrict__ dw1_b,
    const float* __restrict__ w_in, const float* __restrict__ dw2_w, const float* __restrict__ w_out,
    const float* __restrict__ w_off, const float* __restrict__ w_mask,
    const float* __restrict__ raw_sigma,
    const float* __restrict__ k0w, const float* __restrict__ k0b,
    const float* __restrict__ k1w, const float* __restrict__ k1b,
    const float* __restrict__ k2w, const float* __restrict__ k2b,
    const float* __restrict__ k3w, const float* __restrict__ k3b,
    const float* __restrict__ b_off, const float* __restrict__ b_mask,
    __hip_bfloat16* __restrict__ xbf, __hip_bfloat16* __restrict__ hbf,
    __hip_bfloat16* __restrict__ wtin, __hip_bfloat16* __restrict__ wtdw2,
    __hip_bfloat16* __restrict__ wtout, __hip_bfloat16* __restrict__ wtcomb,
    float* __restrict__ kws2, float* __restrict__ bcomb)
{
    const int bid = blockIdx.x;
    const int tid = threadIdx.x;
    __shared__ float t[64][65];
    __shared__ float envs_sh[8];
    __shared__ float h0[KK][HIDN];
    __shared__ float h1[KK][HIDN];
    __shared__ float h2[KK][HIDN];
    __shared__ float flatw[NOFF];

    if (bid < NDWB) {
        size_t base = ((size_t)bid * 256 + tid) * 4;
        int c = (int)(base & (CCH - 1));
        int l = (int)((base >> 8) & (LL - 1));
        float4 xm = *(const float4*)&x[base];
        float4 xl = make_float4(0.f, 0.f, 0.f, 0.f);
        float4 xr = make_float4(0.f, 0.f, 0.f, 0.f);
        if (l > 0)      xl = *(const float4*)&x[base - CCH];
        if (l < LL - 1) xr = *(const float4*)&x[base + CCH];
        float vm[4] = {xm.x, xm.y, xm.z, xm.w};
        float vl[4] = {xl.x, xl.y, xl.z, xl.w};
        float vr[4] = {xr.x, xr.y, xr.z, xr.w};
        ushort xo[4], ho[4];
        #pragma unroll
        for (int j = 0; j < 4; ++j) {
            int cc = c + j;
            float s = vm[j] * dw1_w[cc * 3 + 1] + vl[j] * dw1_w[cc * 3 + 0]
                    + vr[j] * dw1_w[cc * 3 + 2] + dw1_b[cc];
            __hip_bfloat16 hb = __float2bfloat16(siluf(s));
            __hip_bfloat16 xb = __float2bfloat16(vm[j]);
            ho[j] = *(ushort*)&hb;
            xo[j] = *(ushort*)&xb;
        }
        *(short4v*)&xbf[base] = *(short4v*)xo;
        *(short4v*)&hbf[base] = *(short4v*)ho;
        return;
    }
    if (bid < NDWB + NPREPB) {
        const int task = (bid - NDWB) / 112;
        const int bx = (bid - NDWB) % 112;
        if (task == 5) {
            if (bx >= 64) return;
            unsigned u = bx * 256 + tid;
            unsigned row_sel = u >> 5, chunk = u & 31;
            unsigned g = row_sel >> 1, which = row_sel & 1;
            unsigned row = g * 16 + 7 + which * 8;
            short8 z = {};
            *(short8*)((ushort*)wtcomb + (size_t)row * 256 + chunk * 8) = z;
            return;
        }
        const float* src; __hip_bfloat16* dst; int N; int mode = 0;
        switch (task) {
            case 0: src = w_in;  dst = wtin;  N = 256;  break;
            case 1: src = dw2_w; dst = wtdw2; N = 256;  break;
            case 2: src = w_out; dst = wtout; N = 256;  break;
            case 3: src = w_off;  dst = wtcomb; N = NOFF; mode = 1; break;
            default: src = w_mask; dst = wtcomb; N = NOFF; mode = 2; break;
        }
        int ntiles = 4 * (N / 64);
        if (bx >= ntiles) return;
        if (mode == 2 && tid == 0) compute_env(raw_sigma, envs_sh);
        int tk = (bx & 3) * 64;
        int tn = (bx >> 2) * 64;
        #pragma unroll
        for (int i = 0; i < 16; ++i) {
            int e = i * 256 + tid, kk = e >> 6, nn = e & 63;
            t[kk][nn] = src[(size_t)(tk + kk) * N + tn + nn];
        }
        __syncthreads();
        #pragma unroll
        for (int i = 0; i < 16; ++i) {
            int e = i * 256 + tid, nn = e >> 6, kk = e & 63;
            int c = tn + nn;
            float v = t[kk][nn];
            int cp;
            if (mode == 0) cp = c;
            else {
                int g = c / KK, k = c % KK;
                if (mode == 1) { cp = g * 16 + k;     v *= NLOG2E2; }
                else           { cp = g * 16 + 8 + k; v *= envs_sh[k] * LOG2E; }
            }
            dst[(size_t)cp * 256 + tk + kk] = __float2bfloat16(v);
        }
        return;
    }
    {
        int tt = tid;
        if (tt < KK * HIDN) {
            int k = tt / HIDN, j = tt % HIDN;
            float gk = -0.5f + (float)k * (1.0f / 6.0f);
            float v = gk * 30.0f * k0w[j] + k0b[j];
            h0[k][j] = siluf(v);
        }
        __syncthreads();
        if (tt < KK * HIDN) {
            int k = tt / HIDN, j = tt % HIDN;
            float s = k1b[j];
            #pragma unroll
            for (int i = 0; i < HIDN; ++i) s += h0[k][i] * k1w[i * HIDN + j];
            h1[k][j] = siluf(s);
        }
        __syncthreads();
        if (tt < KK * HIDN) {
            int k = tt / HIDN, j = tt % HIDN;
            float s = k2b[j];
            #pragma unroll
            for (int i = 0; i < HIDN; ++i) s += h1[k][i] * k2w[i * HIDN + j];
            h2[k][j] = siluf(s);
        }
        __syncthreads();
        for (int k = 0; k < KK; ++k) {
            float s = k3b[tt];
            #pragma unroll
            for (int i = 0; i < HIDN; ++i) s += h2[k][i] * k3w[i * CCH + tt];
            flatw[k * CCH + tt] = s;
        }
        if (tt == 0) compute_env(raw_sigma, envs_sh);
        __syncthreads();
        #pragma unroll
        for (int k = 0; k < KK; ++k) kws2[tt * 8 + k] = flatw[tt * KK + k];
        kws2[tt * 8 + 7] = 0.0f;
        #pragma unroll
        for (int k = 0; k < KK; ++k) {
            bcomb[tt * 16 + k]     = b_off[tt * KK + k] * NLOG2E2;
            bcomb[tt * 16 + 8 + k] = b_mask[tt * KK + k] * envs_sh[k] * LOG2E;
        }
        bcomb[tt * 16 + 7]  = 0.0f;
        bcomb[tt * 16 + 15] = 0.0f;
    }
}

// ---------------- shared GEMM core (LDS-staged, r11-verified) ----------------
template<int OUTBF>
__device__ __forceinline__ void gemm_core(
    const __hip_bfloat16* __restrict__ A, const __hip_bfloat16* __restrict__ Bt,
    const float* __restrict__ bias, void* __restrict__ C, int N, char* lds,
    int bx, int by)
{
    char* As = lds;
    char* Bs = lds + 16384;
    const int tid = threadIdx.x, lane = tid & 63, w = tid >> 6;
    const int wr = w >> 1, wc = w & 1;
    const size_t m0 = (size_t)by * 128, n0 = (size_t)bx * 128;

    const int srow = w * 32 + (lane >> 3);
    const int sgr  = (lane & 7) ^ ((lane >> 3) & 7);
    const __hip_bfloat16* a_src = A  + (m0 + srow) * 256 + sgr * 8;
    const __hip_bfloat16* b_src = Bt + (n0 + srow) * 256 + sgr * 8;
    char* a_dst = As + (w * 32) * 128;
    char* b_dst = Bs + (w * 32) * 128;

    f32x4 acc[4][4] = {};

    for (int kt = 0; kt < 4; ++kt) {
        const int k0 = kt * 64;
        #pragma unroll
        for (int inst = 0; inst < 4; ++inst) {
            __builtin_amdgcn_global_load_lds((gvoid_t*)(a_src + k0 + (size_t)inst * 8 * 256),
                                             (svoid_t*)(a_dst + inst * 1024), 16, 0, 0);
            __builtin_amdgcn_global_load_lds((gvoid_t*)(b_src + k0 + (size_t)inst * 8 * 256),
                                             (svoid_t*)(b_dst + inst * 1024), 16, 0, 0);
        }
        __syncthreads();
        #pragma unroll
        for (int ks = 0; ks < 2; ++ks) {
            short8 a[4], b[4];
            #pragma unroll
            for (int i = 0; i < 4; ++i) {
                int mr = wr * 64 + i * 16 + (lane & 15);
                int gk = ks * 4 + (lane >> 4);
                a[i] = *(const short8*)(As + mr * 128 + ((gk ^ (mr & 7)) << 4));
                int nr = wc * 64 + i * 16 + (lane & 15);
                b[i] = *(const short8*)(Bs + nr * 128 + ((gk ^ (nr & 7)) << 4));
            }
            #pragma unroll
            for (int i = 0; i < 4; ++i)
                #pragma unroll
                for (int j = 0; j < 4; ++j)
                    acc[i][j] = __builtin_amdgcn_mfma_f32_16x16x32_bf16(a[i], b[j], acc[i][j], 0, 0, 0);
        }
        __syncthreads();
    }
    #pragma unroll
    for (int j = 0; j < 4; ++j) {
        int col = (int)n0 + wc * 64 + j * 16 + (lane & 15);
        float bb = bias[col];
        #pragma unroll
        for (int i = 0; i < 4; ++i) {
            size_t row0 = m0 + wr * 64 + i * 16 + ((lane >> 4) << 2);
            f32x4 v = acc[i][j];
            #pragma unroll
            for (int q = 0; q < 4; ++q) {
                float val = v[q] + bb;
                if (OUTBF) ((__hip_bfloat16*)C)[(row0 + q) * N + col] = __float2bfloat16(val);
                else       ((float*)C)[(row0 + q) * N + col] = val;
            }
        }
    }
}

// dual small GEMM: z=0 -> x_proj, z=1 -> x_dw (independent, one dispatch)
__global__ __launch_bounds__(256) void gemm_dual_k256(
    const __hip_bfloat16* __restrict__ A0, const __hip_bfloat16* __restrict__ Bt0,
    const float* __restrict__ bias0, __hip_bfloat16* __restrict__ C0,
    const __hip_bfloat16* __restrict__ A1, const __hip_bfloat16* __restrict__ Bt1,
    const float* __restrict__ bias1, __hip_bfloat16* __restrict__ C1)
{
    __shared__ __align__(16) char lds[32768];
    if (blockIdx.z == 0) gemm_core<1>(A0, Bt0, bias0, C0, 256, lds, blockIdx.x, blockIdx.y);
    else                 gemm_core<1>(A1, Bt1, bias1, C1, 256, lds, blockIdx.x, blockIdx.y);
}

// out GEMM + finalize tail block (by==128)
__global__ __launch_bounds__(256) void gemm_out_k256(
    const __hip_bfloat16* __restrict__ A, const __hip_bfloat16* __restrict__ Bt,
    const float* __restrict__ bias, float* __restrict__ C,
    const float* __restrict__ partials, float* __restrict__ out_tail)
{
    __shared__ __align__(16) char lds[32768];
    if (blockIdx.y == 128) {
        if (blockIdx.x != 0) return;
        __shared__ float redr[256], rede[256];
        int t = threadIdx.x;
        float r = 0.0f, e = 0.0f;
        for (int i = t; i < NBLK; i += 256) {
            r += partials[2 * i];
            e += partials[2 * i + 1];
        }
        redr[t] = r; rede[t] = e;
        __syncthreads();
        for (int s = 128; s > 0; s >>= 1) {
            if (t < s) { redr[t] += redr[t + s]; rede[t] += rede[t + s]; }
            __syncthreads();
        }
        if (t == 0) {
            out_tail[0] = redr[0] / 29360128.0f;   // B*L*G*K
            out_tail[1] = rede[0] / 4194304.0f;    // B*L*G
        }
        return;
    }
    gemm_core<0>(A, Bt, bias, C, 256, lds, blockIdx.x, blockIdx.y);
}

// ---------------- fused off|mask GEMM + LDS-C-tile tanh/gather/softmax epilogue ----------------
// r11 structure exactly; only change: softmax without max-subtraction (validated r13/r14).
__global__ __launch_bounds__(256) void gemm_fused_sample(
    const __hip_bfloat16* __restrict__ A,      // xdw [16384][256]
    const __hip_bfloat16* __restrict__ Bt,     // wtcomb [4096][256] prescaled
    const float* __restrict__ bcomb,           // [4096] prescaled padded biases
    const __hip_bfloat16* __restrict__ xproj,  // [4][4096][256]
    const float* __restrict__ kws2,            // [256][8] kw, pad k=7 -> 0
    __hip_bfloat16* __restrict__ out_pre,
    float* __restrict__ partials)              // [NBLK][2]
{
    __shared__ __align__(16) char lds[35072];   // 32KB GEMM/Cs + 2.25KB Xs
    char* As = lds;
    char* Bs = lds + 16384;
    const int tid = threadIdx.x, lane = tid & 63, w = tid >> 6;
    const int wr = w >> 1, wc = w & 1;
    // XCD-aware bijective swizzle: each XCD gets 16 contiguous m-panels (A reuse in L2)
    const int flat = blockIdx.y * 32 + blockIdx.x;
    const int wid = ((flat & 7) << 9) | (flat >> 3);
    const int bx = wid & 31, by = wid >> 5;
    const size_t m0 = (size_t)by * 128;
    const int n0 = bx * 128, g0 = bx * 8;
    const int l0 = (int)(m0 & (LL - 1));
    const int bidx = (int)(m0 >> 12);

    // stage Xs (xproj rows l0-5..l0+134, 8 cols) async; completes by first GEMM barrier
    if (tid < 140) {
        int rr = min(max(l0 - 5 + tid, 0), LL - 1);
        const ushort* src = (const ushort*)xproj + ((size_t)bidx * LL + rr) * CCH + g0;
        __builtin_amdgcn_global_load_lds((gvoid_t*)src,
            (svoid_t*)(lds + 32768 + (tid >> 6) * 1024), 16, 0, 0);
    }

    const int srow = w * 32 + (lane >> 3);
    const int sgr  = (lane & 7) ^ ((lane >> 3) & 7);
    const __hip_bfloat16* a_src = A  + (m0 + srow) * 256 + sgr * 8;
    const __hip_bfloat16* b_src = Bt + (size_t)(n0 + srow) * 256 + sgr * 8;
    char* a_dst = As + (w * 32) * 128;
    char* b_dst = Bs + (w * 32) * 128;

    f32x4 acc[4][4] = {};   // acc[j][i], operand-swapped

    for (int kt = 0; kt < 4; ++kt) {
        const int k0 = kt * 64;
        #pragma unroll
        for (int inst = 0; inst < 4; ++inst) {
            __builtin_amdgcn_global_load_lds((gvoid_t*)(a_src + k0 + (size_t)inst * 8 * 256),
                                             (svoid_t*)(a_dst + inst * 1024), 16, 0, 0);
            __builtin_amdgcn_global_load_lds((gvoid_t*)(b_src + k0 + (size_t)inst * 8 * 256),
                                             (svoid_t*)(b_dst + inst * 1024), 16, 0, 0);
        }
        __syncthreads();
        #pragma unroll
        for (int ks = 0; ks < 2; ++ks) {
            short8 a[4], b[4];
            #pragma unroll
            for (int i = 0; i < 4; ++i) {
                int mr = wr * 64 + i * 16 + (lane & 15);
                int gk = ks * 4 + (lane >> 4);
                a[i] = *(const short8*)(As + mr * 128 + ((gk ^ (mr & 7)) << 4));
                int nr = wc * 64 + i * 16 + (lane & 15);
                b[i] = *(const short8*)(Bs + nr * 128 + ((gk ^ (nr & 7)) << 4));
            }
            #pragma unroll
            for (int i = 0; i < 4; ++i)
                #pragma unroll
                for (int j = 0; j < 4; ++j)
                    acc[j][i] = __builtin_amdgcn_mfma_f32_16x16x32_bf16(b[j], a[i], acc[j][i], 0, 0, 0);
        }
        __syncthreads();
    }

    // ---- epilogue 1: bias + fp16 pack, b64 store into swizzled Cs (reuses As/Bs) ----
    {
        const int rl = lane & 15, grp = lane >> 4;
        #pragma unroll
        for (int j = 0; j < 4; ++j) {
            float4 bi = *(const float4*)&bcomb[n0 + wc * 64 + j * 16 + grp * 4];
            const int gran = wc * 8 + j * 2 + (grp >> 1);
            #pragma unroll
            for (int i = 0; i < 4; ++i) {
                f32x4 v = acc[j][i];
                uint2 pk;
                pk.x = pkh(v[0] + bi.x, v[1] + bi.y);
                pk.y = pkh(v[2] + bi.z, v[3] + bi.w);
                int row = wr * 64 + i * 16 + rl;
                int addr = row * 256 + ((gran ^ rl) << 4) + (grp & 1) * 8;
                *(uint2*)(lds + addr) = pk;
            }
        }
    }
    __syncthreads();

    // ---- epilogue 2: 4 points/thread (softmax without max-subtraction) ----
    const ushort* XsL = (const ushort*)(lds + 32768);
    const int gg = tid & 7, rb = tid >> 3;   // rb 0..31
    float kwv[KK];
    {
        const float* kp = &kws2[(size_t)(g0 + gg) * 8];
        float4 ka = *(const float4*)kp;
        float4 kb = *(const float4*)(kp + 4);
        kwv[0] = ka.x; kwv[1] = ka.y; kwv[2] = ka.z; kwv[3] = ka.w;
        kwv[4] = kb.x; kwv[5] = kb.y; kwv[6] = kb.z;
    }
    float reg_acc = 0.0f, ent_acc = 0.0f;
    #pragma unroll
    for (int pp = 0; pp < 4; ++pp) {
        const int r = rb + 32 * pp;
        short8 ca = *(const short8*)(lds + r * 256 + (((2 * gg) ^ (r & 15)) << 4));
        short8 cb = *(const short8*)(lds + r * 256 + (((2 * gg + 1) ^ (r & 15)) << 4));
        const int l = l0 + r;
        float es = 0.0f, tacc = 0.0f, o = 0.0f;
        #pragma unroll
        for (int k = 0; k < KK; ++k) {
            float mvk = h2f((ushort)cb[k]);        // env-scaled logit; small, no max-sub
            float e = exp2f(mvk);
            es += e; tacc += e * mvk;
            float zp = fminf(h2f((ushort)ca[k]), 80.f);   // = -2z*log2e (one-sided clamp)
            float ee = exp2f(zp);                          // = exp(-2z)
            float ov = 2.0f * (1.0f - ee) * rcpf(1.0f + ee);   // = 2*tanh(z)
            reg_acc += ov * ov;
            float p = fminf(fmaxf((float)(l + k - 3) + ov, 0.0f), 4095.0f);
            int pf = (int)p;
            float wcf = p - (float)pf;
            int ix = pf - (l0 - 5);
            float sv = bf2f(XsL[ix * 8 + gg]) * (1.0f - wcf) + bf2f(XsL[ix * 8 + 8 + gg]) * wcf;
            o += sv * kwv[k] * e;
        }
        float inv = rcpf(es);
        ent_acc += tacc * inv - __log2f(es);
        out_pre[(m0 + r) * CCH + g0 + gg] = __float2bfloat16(o * inv);
    }

    // wave butterfly, then per-block partial via LDS (no atomics)
    #pragma unroll
    for (int d = 1; d < 64; d <<= 1) {
        reg_acc += __shfl_xor(reg_acc, d);
        ent_acc += __shfl_xor(ent_acc, d);
    }
    __syncthreads();                       // all Cs/Xs reads complete before LDS reuse
    float* redv = (float*)lds;
    if (lane == 0) { redv[w] = reg_acc; redv[4 + w] = ent_acc; }
    __syncthreads();
    if (tid == 0) {
        float r2 = redv[0] + redv[1] + redv[2] + redv[3];
        float e2 = redv[4] + redv[5] + redv[6] + redv[7];
        partials[wid * 2]     = r2;
        partials[wid * 2 + 1] = e2 * LN2;
    }
}

extern "C" void kernel_launch(void* const* d_in, const int* in_sizes, int n_in,
                              void* d_out, int out_size, void* d_ws, size_t ws_size,
                              hipStream_t stream)
{
    const float* x         = (const float*)d_in[0];
    const float* raw_sigma = (const float*)d_in[1];
    const float* w_in      = (const float*)d_in[2];
    const float* b_in      = (const float*)d_in[3];
    const float* w_out     = (const float*)d_in[4];
    const float* b_out     = (const float*)d_in[5];
    const float* dw1_w     = (const float*)d_in[6];
    const float* dw1_b     = (const float*)d_in[7];
    const float* dw2_w     = (const float*)d_in[8];
    const float* dw2_b     = (const float*)d_in[9];
    const float* w_off     = (const float*)d_in[10];
    const float* b_off     = (const float*)d_in[11];
    const float* w_mask    = (const float*)d_in[12];
    const float* b_mask    = (const float*)d_in[13];
    const float* k0w       = (const float*)d_in[14];
    const float* k0b       = (const float*)d_in[15];
    const float* k1w       = (const float*)d_in[16];
    const float* k1b       = (const float*)d_in[17];
    const float* k2w       = (const float*)d_in[18];
    const float* k2b       = (const float*)d_in[19];
    const float* k3w       = (const float*)d_in[20];
    const float* k3b       = (const float*)d_in[21];

    char* ws = (char*)d_ws;
    const size_t MB8 = (size_t)8 * 1024 * 1024;
    __hip_bfloat16* xbf    = (__hip_bfloat16*)(ws + 0);
    __hip_bfloat16* hbf    = (__hip_bfloat16*)(ws + MB8);        // h, reused as out_pre
    __hip_bfloat16* xdwbf  = (__hip_bfloat16*)(ws + 2 * MB8);
    __hip_bfloat16* xprojb = (__hip_bfloat16*)(ws + 3 * MB8);
    char* wbase = ws + 4 * MB8;
    __hip_bfloat16* wtin   = (__hip_bfloat16*)(wbase);                    // 128KB
    __hip_bfloat16* wtdw2  = (__hip_bfloat16*)(wbase + 131072);           // 128KB
    __hip_bfloat16* wtout  = (__hip_bfloat16*)(wbase + 262144);           // 128KB
    __hip_bfloat16* wtcomb = (__hip_bfloat16*)(wbase + 393216);           // 4096*256*2 = 2MB
    float* bcomb    = (float*)(wbase + 393216 + 2097152);                 // 4096 floats
    float* kws2     = bcomb + NP;                                         // 2048 floats
    float* partials = kws2 + 2048;                                        // 8192 floats

    // 1) merged pre-work: dwconv+xbf | weight transposes | kernel-net (one dispatch)
    pre_kernel<<<NDWB + NPREPB + 1, 256, 0, stream>>>(
        x, dw1_w, dw1_b, w_in, dw2_w, w_out, w_off, w_mask, raw_sigma,
        k0w, k0b, k1w, k1b, k2w, k2b, k3w, k3b, b_off, b_mask,
        xbf, hbf, wtin, wtdw2, wtout, wtcomb, kws2, bcomb);
    // 2) x_proj and x_dw in one dispatch
    gemm_dual_k256<<<dim3(2, 128, 2), 256, 0, stream>>>(xbf, wtin, b_in, xprojb,
                                                        hbf, wtdw2, dw2_b, xdwbf);
    // 3) fused off|mask GEMM + LDS-tile sampling/softmax  (out_pre -> hbf, partials out)
    gemm_fused_sample<<<dim3(NP / 128, MTOT / 128), 256, 0, stream>>>(
        xdwbf, wtcomb, bcomb, xprojb, kws2, hbf, partials);
    // 4) out = out_pre @ w_out + b_out (fp32) + finalize tail block
    gemm_out_k256<<<dim3(2, 129), 256, 0, stream>>>(hbf, wtout, b_out, (float*)d_out,
                                                    partials, (float*)d_out + (size_t)MTOT * CCH);
}

// Round 16
// 120.263 us; speedup vs baseline: 1.0968x; 1.0325x over previous
//
#include <hip/hip_runtime.h>
#include <hip/hip_bf16.h>
#include <hip/hip_fp16.h>
#include <math.h>

#define BB   4
#define LL   4096
#define CCH  256
#define KK   7
#define HIDN 32
#define MTOT (BB * LL)          // 16384 rows
#define NOFF (CCH * KK)         // 1792
#define NP   4096               // padded fused N: col = g*16 + idx (0..6 off, 7 pad, 8..14 mask, 15 pad)
#define NBLK ((NP / 128) * (MTOT / 128))   // 4096 fused blocks
#define NDWB 4096               // dwconv blocks
#define NPREPB 672              // prep blocks (6 tasks x 112)

#define LOG2E  1.4426950408889634f
#define NLOG2E2 (-2.8853900817779268f)   // -2*log2(e)
#define LN2    0.6931471805599453f

typedef __attribute__((ext_vector_type(8))) short short8;
typedef __attribute__((ext_vector_type(4))) short short4v;
typedef __attribute__((ext_vector_type(4))) float f32x4;
typedef __attribute__((ext_vector_type(2))) __fp16 fp16x2;
typedef __attribute__((address_space(1))) void gvoid_t;
typedef __attribute__((address_space(3))) void svoid_t;

__device__ __forceinline__ float siluf(float v) { return v / (1.0f + expf(-v)); }
__device__ __forceinline__ float bf2f(ushort u) { unsigned x = (unsigned)u << 16; return __uint_as_float(x); }
__device__ __forceinline__ float h2f(ushort u) { __half_raw hr; hr.x = u; return __half2float(__half(hr)); }
__device__ __forceinline__ float rcpf(float x) { return __builtin_amdgcn_rcpf(x); }
__device__ __forceinline__ unsigned pkh(float a, float b) {
    union { fp16x2 h; unsigned u; } cv;
    cv.h = __builtin_amdgcn_cvt_pkrtz(a, b);
    return cv.u;
}
__device__ __forceinline__ void compute_env(const float* raw_sigma, float* ev) {
    float sp = log1pf(expf(raw_sigma[0]));
    sp = fminf(fmaxf(sp, 0.05f), 0.5f);
    float sg = fmaxf(sp, 1e-6f);
    float ssum = 0.0f;
    for (int k = 0; k < KK; ++k) {
        float gk = -0.5f + (float)k * (1.0f / 6.0f);
        float d = gk / sg;
        ev[k] = expf(-0.5f * d * d);
        ssum += ev[k];
    }
    ssum = fmaxf(ssum, 1e-8f);
    for (int k = 0; k < KK; ++k) ev[k] /= ssum;
}

// ============ merged pre-work: dwconv+xbf | weight transposes | kernel-net precompute ============
__global__ __launch_bounds__(256) void pre_kernel(
    const float* __restrict__ x, const float* __restrict__ dw1_w, const float* __restrict__ dw1_b,
    const float* __restrict__ w_in, const float* __restrict__ dw2_w, const float* __restrict__ w_out,
    const float* __restrict__ w_off, const float* __restrict__ w_mask,
    const float* __restrict__ raw_sigma,
    const float* __restrict__ k0w, const float* __restrict__ k0b,
    const float* __restrict__ k1w, const float* __restrict__ k1b,
    const float* __restrict__ k2w, const float* __restrict__ k2b,
    const float* __restrict__ k3w, const float* __restrict__ k3b,
    const float* __restrict__ b_off, const float* __restrict__ b_mask,
    __hip_bfloat16* __restrict__ xbf, __hip_bfloat16* __restrict__ hbf,
    __hip_bfloat16* __restrict__ wtin, __hip_bfloat16* __restrict__ wtdw2,
    __hip_bfloat16* __restrict__ wtout, __hip_bfloat16* __restrict__ wtcomb,
    float* __restrict__ kws2, float* __restrict__ bcomb)
{
    const int bid = blockIdx.x;
    const int tid = threadIdx.x;
    __shared__ float t[64][65];
    __shared__ float envs_sh[8];
    __shared__ float h0[KK][HIDN];
    __shared__ float h1[KK][HIDN];
    __shared__ float h2[KK][HIDN];
    __shared__ float flatw[NOFF];

    if (bid < NDWB) {
        size_t base = ((size_t)bid * 256 + tid) * 4;
        int c = (int)(base & (CCH - 1));
        int l = (int)((base >> 8) & (LL - 1));
        float4 xm = *(const float4*)&x[base];
        float4 xl = make_float4(0.f, 0.f, 0.f, 0.f);
        float4 xr = make_float4(0.f, 0.f, 0.f, 0.f);
        if (l > 0)      xl = *(const float4*)&x[base - CCH];
        if (l < LL - 1) xr = *(const float4*)&x[base + CCH];
        float vm[4] = {xm.x, xm.y, xm.z, xm.w};
        float vl[4] = {xl.x, xl.y, xl.z, xl.w};
        float vr[4] = {xr.x, xr.y, xr.z, xr.w};
        ushort xo[4], ho[4];
        #pragma unroll
        for (int j = 0; j < 4; ++j) {
            int cc = c + j;
            float s = vm[j] * dw1_w[cc * 3 + 1] + vl[j] * dw1_w[cc * 3 + 0]
                    + vr[j] * dw1_w[cc * 3 + 2] + dw1_b[cc];
            __hip_bfloat16 hb = __float2bfloat16(siluf(s));
            __hip_bfloat16 xb = __float2bfloat16(vm[j]);
            ho[j] = *(ushort*)&hb;
            xo[j] = *(ushort*)&xb;
        }
        *(short4v*)&xbf[base] = *(short4v*)xo;
        *(short4v*)&hbf[base] = *(short4v*)ho;
        return;
    }
    if (bid < NDWB + NPREPB) {
        const int task = (bid - NDWB) / 112;
        const int bx = (bid - NDWB) % 112;
        if (task == 5) {
            if (bx >= 64) return;
            unsigned u = bx * 256 + tid;
            unsigned row_sel = u >> 5, chunk = u & 31;
            unsigned g = row_sel >> 1, which = row_sel & 1;
            unsigned row = g * 16 + 7 + which * 8;
            short8 z = {};
            *(short8*)((ushort*)wtcomb + (size_t)row * 256 + chunk * 8) = z;
            return;
        }
        const float* src; __hip_bfloat16* dst; int N; int mode = 0;
        switch (task) {
            case 0: src = w_in;  dst = wtin;  N = 256;  break;
            case 1: src = dw2_w; dst = wtdw2; N = 256;  break;
            case 2: src = w_out; dst = wtout; N = 256;  break;
            case 3: src = w_off;  dst = wtcomb; N = NOFF; mode = 1; break;
            default: src = w_mask; dst = wtcomb; N = NOFF; mode = 2; break;
        }
        int ntiles = 4 * (N / 64);
        if (bx >= ntiles) return;
        if (mode == 2 && tid == 0) compute_env(raw_sigma, envs_sh);
        int tk = (bx & 3) * 64;
        int tn = (bx >> 2) * 64;
        #pragma unroll
        for (int i = 0; i < 16; ++i) {
            int e = i * 256 + tid, kk = e >> 6, nn = e & 63;
            t[kk][nn] = src[(size_t)(tk + kk) * N + tn + nn];
        }
        __syncthreads();
        #pragma unroll
        for (int i = 0; i < 16; ++i) {
            int e = i * 256 + tid, nn = e >> 6, kk = e & 63;
            int c = tn + nn;
            float v = t[kk][nn];
            int cp;
            if (mode == 0) cp = c;
            else {
                int g = c / KK, k = c % KK;
                if (mode == 1) { cp = g * 16 + k;     v *= NLOG2E2; }
                else           { cp = g * 16 + 8 + k; v *= envs_sh[k] * LOG2E; }
            }
            dst[(size_t)cp * 256 + tk + kk] = __float2bfloat16(v);
        }
        return;
    }
    {
        int tt = tid;
        if (tt < KK * HIDN) {
            int k = tt / HIDN, j = tt % HIDN;
            float gk = -0.5f + (float)k * (1.0f / 6.0f);
            float v = gk * 30.0f * k0w[j] + k0b[j];
            h0[k][j] = siluf(v);
        }
        __syncthreads();
        if (tt < KK * HIDN) {
            int k = tt / HIDN, j = tt % HIDN;
            float s = k1b[j];
            #pragma unroll
            for (int i = 0; i < HIDN; ++i) s += h0[k][i] * k1w[i * HIDN + j];
            h1[k][j] = siluf(s);
        }
        __syncthreads();
        if (tt < KK * HIDN) {
            int k = tt / HIDN, j = tt % HIDN;
            float s = k2b[j];
            #pragma unroll
            for (int i = 0; i < HIDN; ++i) s += h1[k][i] * k2w[i * HIDN + j];
            h2[k][j] = siluf(s);
        }
        __syncthreads();
        for (int k = 0; k < KK; ++k) {
            float s = k3b[tt];
            #pragma unroll
            for (int i = 0; i < HIDN; ++i) s += h2[k][i] * k3w[i * CCH + tt];
            flatw[k * CCH + tt] = s;
        }
        if (tt == 0) compute_env(raw_sigma, envs_sh);
        __syncthreads();
        #pragma unroll
        for (int k = 0; k < KK; ++k) kws2[tt * 8 + k] = flatw[tt * KK + k];
        kws2[tt * 8 + 7] = 0.0f;
        #pragma unroll
        for (int k = 0; k < KK; ++k) {
            bcomb[tt * 16 + k]     = b_off[tt * KK + k] * NLOG2E2;
            bcomb[tt * 16 + 8 + k] = b_mask[tt * KK + k] * envs_sh[k] * LOG2E;
        }
        bcomb[tt * 16 + 7]  = 0.0f;
        bcomb[tt * 16 + 15] = 0.0f;
    }
}

// ---------------- shared GEMM core (LDS-staged, r11-verified) ----------------
template<int OUTBF>
__device__ __forceinline__ void gemm_core(
    const __hip_bfloat16* __restrict__ A, const __hip_bfloat16* __restrict__ Bt,
    const float* __restrict__ bias, void* __restrict__ C, int N, char* lds,
    int bx, int by)
{
    char* As = lds;
    char* Bs = lds + 16384;
    const int tid = threadIdx.x, lane = tid & 63, w = tid >> 6;
    const int wr = w >> 1, wc = w & 1;
    const size_t m0 = (size_t)by * 128, n0 = (size_t)bx * 128;

    const int srow = w * 32 + (lane >> 3);
    const int sgr  = (lane & 7) ^ ((lane >> 3) & 7);
    const __hip_bfloat16* a_src = A  + (m0 + srow) * 256 + sgr * 8;
    const __hip_bfloat16* b_src = Bt + (n0 + srow) * 256 + sgr * 8;
    char* a_dst = As + (w * 32) * 128;
    char* b_dst = Bs + (w * 32) * 128;

    f32x4 acc[4][4] = {};

    for (int kt = 0; kt < 4; ++kt) {
        const int k0 = kt * 64;
        #pragma unroll
        for (int inst = 0; inst < 4; ++inst) {
            __builtin_amdgcn_global_load_lds((gvoid_t*)(a_src + k0 + (size_t)inst * 8 * 256),
                                             (svoid_t*)(a_dst + inst * 1024), 16, 0, 0);
            __builtin_amdgcn_global_load_lds((gvoid_t*)(b_src + k0 + (size_t)inst * 8 * 256),
                                             (svoid_t*)(b_dst + inst * 1024), 16, 0, 0);
        }
        __syncthreads();
        #pragma unroll
        for (int ks = 0; ks < 2; ++ks) {
            short8 a[4], b[4];
            #pragma unroll
            for (int i = 0; i < 4; ++i) {
                int mr = wr * 64 + i * 16 + (lane & 15);
                int gk = ks * 4 + (lane >> 4);
                a[i] = *(const short8*)(As + mr * 128 + ((gk ^ (mr & 7)) << 4));
                int nr = wc * 64 + i * 16 + (lane & 15);
                b[i] = *(const short8*)(Bs + nr * 128 + ((gk ^ (nr & 7)) << 4));
            }
            #pragma unroll
            for (int i = 0; i < 4; ++i)
                #pragma unroll
                for (int j = 0; j < 4; ++j)
                    acc[i][j] = __builtin_amdgcn_mfma_f32_16x16x32_bf16(a[i], b[j], acc[i][j], 0, 0, 0);
        }
        __syncthreads();
    }
    #pragma unroll
    for (int j = 0; j < 4; ++j) {
        int col = (int)n0 + wc * 64 + j * 16 + (lane & 15);
        float bb = bias[col];
        #pragma unroll
        for (int i = 0; i < 4; ++i) {
            size_t row0 = m0 + wr * 64 + i * 16 + ((lane >> 4) << 2);
            f32x4 v = acc[i][j];
            #pragma unroll
            for (int q = 0; q < 4; ++q) {
                float val = v[q] + bb;
                if (OUTBF) ((__hip_bfloat16*)C)[(row0 + q) * N + col] = __float2bfloat16(val);
                else       ((float*)C)[(row0 + q) * N + col] = val;
            }
        }
    }
}

// dual small GEMM: z=0 -> x_proj, z=1 -> x_dw. XCD-bijective swizzle (256 = 8 x 32).
__global__ __launch_bounds__(256) void gemm_dual_k256(
    const __hip_bfloat16* __restrict__ A0, const __hip_bfloat16* __restrict__ Bt0,
    const float* __restrict__ bias0, __hip_bfloat16* __restrict__ C0,
    const __hip_bfloat16* __restrict__ A1, const __hip_bfloat16* __restrict__ Bt1,
    const float* __restrict__ bias1, __hip_bfloat16* __restrict__ C1)
{
    __shared__ __align__(16) char lds[32768];
    const int flat = blockIdx.y * 2 + blockIdx.x;
    const int wid = ((flat & 7) << 5) | (flat >> 3);
    const int bx = wid & 1, by = wid >> 1;
    if (blockIdx.z == 0) gemm_core<1>(A0, Bt0, bias0, C0, 256, lds, bx, by);
    else                 gemm_core<1>(A1, Bt1, bias1, C1, 256, lds, bx, by);
}

// out GEMM + finalize tail block (by==128). XCD swizzle on the 256 GEMM blocks.
__global__ __launch_bounds__(256) void gemm_out_k256(
    const __hip_bfloat16* __restrict__ A, const __hip_bfloat16* __restrict__ Bt,
    const float* __restrict__ bias, float* __restrict__ C,
    const float* __restrict__ partials, float* __restrict__ out_tail)
{
    __shared__ __align__(16) char lds[32768];
    if (blockIdx.y == 128) {
        if (blockIdx.x != 0) return;
        __shared__ float redr[256], rede[256];
        int t = threadIdx.x;
        float r = 0.0f, e = 0.0f;
        for (int i = t; i < NBLK; i += 256) {
            r += partials[2 * i];
            e += partials[2 * i + 1];
        }
        redr[t] = r; rede[t] = e;
        __syncthreads();
        for (int s = 128; s > 0; s >>= 1) {
            if (t < s) { redr[t] += redr[t + s]; rede[t] += rede[t + s]; }
            __syncthreads();
        }
        if (t == 0) {
            out_tail[0] = redr[0] / 29360128.0f;   // B*L*G*K
            out_tail[1] = rede[0] / 4194304.0f;    // B*L*G
        }
        return;
    }
    const int flat = blockIdx.y * 2 + blockIdx.x;
    const int wid = ((flat & 7) << 5) | (flat >> 3);
    gemm_core<0>(A, Bt, bias, C, 256, lds, wid & 1, wid >> 1);
}

// ---------------- fused off|mask GEMM + LDS-C-tile tanh/gather/softmax epilogue ----------------
// r15 structure exactly; only change: s_setprio(1) around the MFMA cluster (cross-block
// phase diversity on each CU: GEMM-phase waves get issue priority over epilogue waves).
__global__ __launch_bounds__(256) void gemm_fused_sample(
    const __hip_bfloat16* __restrict__ A,      // xdw [16384][256]
    const __hip_bfloat16* __restrict__ Bt,     // wtcomb [4096][256] prescaled
    const float* __restrict__ bcomb,           // [4096] prescaled padded biases
    const __hip_bfloat16* __restrict__ xproj,  // [4][4096][256]
    const float* __restrict__ kws2,            // [256][8] kw, pad k=7 -> 0
    __hip_bfloat16* __restrict__ out_pre,
    float* __restrict__ partials)              // [NBLK][2]
{
    __shared__ __align__(16) char lds[35072];   // 32KB GEMM/Cs + 2.25KB Xs
    char* As = lds;
    char* Bs = lds + 16384;
    const int tid = threadIdx.x, lane = tid & 63, w = tid >> 6;
    const int wr = w >> 1, wc = w & 1;
    // XCD-aware bijective swizzle: each XCD gets 16 contiguous m-panels (A reuse in L2)
    const int flat = blockIdx.y * 32 + blockIdx.x;
    const int wid = ((flat & 7) << 9) | (flat >> 3);
    const int bx = wid & 31, by = wid >> 5;
    const size_t m0 = (size_t)by * 128;
    const int n0 = bx * 128, g0 = bx * 8;
    const int l0 = (int)(m0 & (LL - 1));
    const int bidx = (int)(m0 >> 12);

    // stage Xs (xproj rows l0-5..l0+134, 8 cols) async; completes by first GEMM barrier
    if (tid < 140) {
        int rr = min(max(l0 - 5 + tid, 0), LL - 1);
        const ushort* src = (const ushort*)xproj + ((size_t)bidx * LL + rr) * CCH + g0;
        __builtin_amdgcn_global_load_lds((gvoid_t*)src,
            (svoid_t*)(lds + 32768 + (tid >> 6) * 1024), 16, 0, 0);
    }

    const int srow = w * 32 + (lane >> 3);
    const int sgr  = (lane & 7) ^ ((lane >> 3) & 7);
    const __hip_bfloat16* a_src = A  + (m0 + srow) * 256 + sgr * 8;
    const __hip_bfloat16* b_src = Bt + (size_t)(n0 + srow) * 256 + sgr * 8;
    char* a_dst = As + (w * 32) * 128;
    char* b_dst = Bs + (w * 32) * 128;

    f32x4 acc[4][4] = {};   // acc[j][i], operand-swapped

    for (int kt = 0; kt < 4; ++kt) {
        const int k0 = kt * 64;
        #pragma unroll
        for (int inst = 0; inst < 4; ++inst) {
            __builtin_amdgcn_global_load_lds((gvoid_t*)(a_src + k0 + (size_t)inst * 8 * 256),
                                             (svoid_t*)(a_dst + inst * 1024), 16, 0, 0);
            __builtin_amdgcn_global_load_lds((gvoid_t*)(b_src + k0 + (size_t)inst * 8 * 256),
                                             (svoid_t*)(b_dst + inst * 1024), 16, 0, 0);
        }
        __syncthreads();
        #pragma unroll
        for (int ks = 0; ks < 2; ++ks) {
            short8 a[4], b[4];
            #pragma unroll
            for (int i = 0; i < 4; ++i) {
                int mr = wr * 64 + i * 16 + (lane & 15);
                int gk = ks * 4 + (lane >> 4);
                a[i] = *(const short8*)(As + mr * 128 + ((gk ^ (mr & 7)) << 4));
                int nr = wc * 64 + i * 16 + (lane & 15);
                b[i] = *(const short8*)(Bs + nr * 128 + ((gk ^ (nr & 7)) << 4));
            }
            __builtin_amdgcn_s_setprio(1);
            #pragma unroll
            for (int i = 0; i < 4; ++i)
                #pragma unroll
                for (int j = 0; j < 4; ++j)
                    acc[j][i] = __builtin_amdgcn_mfma_f32_16x16x32_bf16(b[j], a[i], acc[j][i], 0, 0, 0);
            __builtin_amdgcn_s_setprio(0);
        }
        __syncthreads();
    }

    // ---- epilogue 1: bias + fp16 pack, b64 store into swizzled Cs (reuses As/Bs) ----
    {
        const int rl = lane & 15, grp = lane >> 4;
        #pragma unroll
        for (int j = 0; j < 4; ++j) {
            float4 bi = *(const float4*)&bcomb[n0 + wc * 64 + j * 16 + grp * 4];
            const int gran = wc * 8 + j * 2 + (grp >> 1);
            #pragma unroll
            for (int i = 0; i < 4; ++i) {
                f32x4 v = acc[j][i];
                uint2 pk;
                pk.x = pkh(v[0] + bi.x, v[1] + bi.y);
                pk.y = pkh(v[2] + bi.z, v[3] + bi.w);
                int row = wr * 64 + i * 16 + rl;
                int addr = row * 256 + ((gran ^ rl) << 4) + (grp & 1) * 8;
                *(uint2*)(lds + addr) = pk;
            }
        }
    }
    __syncthreads();

    // ---- epilogue 2: 4 points/thread (softmax without max-subtraction) ----
    const ushort* XsL = (const ushort*)(lds + 32768);
    const int gg = tid & 7, rb = tid >> 3;   // rb 0..31
    float kwv[KK];
    {
        const float* kp = &kws2[(size_t)(g0 + gg) * 8];
        float4 ka = *(const float4*)kp;
        float4 kb = *(const float4*)(kp + 4);
        kwv[0] = ka.x; kwv[1] = ka.y; kwv[2] = ka.z; kwv[3] = ka.w;
        kwv[4] = kb.x; kwv[5] = kb.y; kwv[6] = kb.z;
    }
    float reg_acc = 0.0f, ent_acc = 0.0f;
    #pragma unroll
    for (int pp = 0; pp < 4; ++pp) {
        const int r = rb + 32 * pp;
        short8 ca = *(const short8*)(lds + r * 256 + (((2 * gg) ^ (r & 15)) << 4));
        short8 cb = *(const short8*)(lds + r * 256 + (((2 * gg + 1) ^ (r & 15)) << 4));
        const int l = l0 + r;
        float es = 0.0f, tacc = 0.0f, o = 0.0f;
        #pragma unroll
        for (int k = 0; k < KK; ++k) {
            float mvk = h2f((ushort)cb[k]);        // env-scaled logit; small, no max-sub
            float e = exp2f(mvk);
            es += e; tacc += e * mvk;
            float zp = fminf(h2f((ushort)ca[k]), 80.f);   // = -2z*log2e (one-sided clamp)
            float ee = exp2f(zp);                          // = exp(-2z)
            float ov = 2.0f * (1.0f - ee) * rcpf(1.0f + ee);   // = 2*tanh(z)
            reg_acc += ov * ov;
            float p = fminf(fmaxf((float)(l + k - 3) + ov, 0.0f), 4095.0f);
            int pf = (int)p;
            float wcf = p - (float)pf;
            int ix = pf - (l0 - 5);
            float sv = bf2f(XsL[ix * 8 + gg]) * (1.0f - wcf) + bf2f(XsL[ix * 8 + 8 + gg]) * wcf;
            o += sv * kwv[k] * e;
        }
        float inv = rcpf(es);
        ent_acc += tacc * inv - __log2f(es);
        out_pre[(m0 + r) * CCH + g0 + gg] = __float2bfloat16(o * inv);
    }

    // wave butterfly, then per-block partial via LDS (no atomics)
    #pragma unroll
    for (int d = 1; d < 64; d <<= 1) {
        reg_acc += __shfl_xor(reg_acc, d);
        ent_acc += __shfl_xor(ent_acc, d);
    }
    __syncthreads();                       // all Cs/Xs reads complete before LDS reuse
    float* redv = (float*)lds;
    if (lane == 0) { redv[w] = reg_acc; redv[4 + w] = ent_acc; }
    __syncthreads();
    if (tid == 0) {
        float r2 = redv[0] + redv[1] + redv[2] + redv[3];
        float e2 = redv[4] + redv[5] + redv[6] + redv[7];
        partials[wid * 2]     = r2;
        partials[wid * 2 + 1] = e2 * LN2;
    }
}

extern "C" void kernel_launch(void* const* d_in, const int* in_sizes, int n_in,
                              void* d_out, int out_size, void* d_ws, size_t ws_size,
                              hipStream_t stream)
{
    const float* x         = (const float*)d_in[0];
    const float* raw_sigma = (const float*)d_in[1];
    const float* w_in      = (const float*)d_in[2];
    const float* b_in      = (const float*)d_in[3];
    const float* w_out     = (const float*)d_in[4];
    const float* b_out     = (const float*)d_in[5];
    const float* dw1_w     = (const float*)d_in[6];
    const float* dw1_b     = (const float*)d_in[7];
    const float* dw2_w     = (const float*)d_in[8];
    const float* dw2_b     = (const float*)d_in[9];
    const float* w_off     = (const float*)d_in[10];
    const float* b_off     = (const float*)d_in[11];
    const float* w_mask    = (const float*)d_in[12];
    const float* b_mask    = (const float*)d_in[13];
    const float* k0w       = (const float*)d_in[14];
    const float* k0b       = (const float*)d_in[15];
    const float* k1w       = (const float*)d_in[16];
    const float* k1b       = (const float*)d_in[17];
    const float* k2w       = (const float*)d_in[18];
    const float* k2b       = (const float*)d_in[19];
    const float* k3w       = (const float*)d_in[20];
    const float* k3b       = (const float*)d_in[21];

    char* ws = (char*)d_ws;
    const size_t MB8 = (size_t)8 * 1024 * 1024;
    __hip_bfloat16* xbf    = (__hip_bfloat16*)(ws + 0);
    __hip_bfloat16* hbf    = (__hip_bfloat16*)(ws + MB8);        // h, reused as out_pre
    __hip_bfloat16* xdwbf  = (__hip_bfloat16*)(ws + 2 * MB8);
    __hip_bfloat16* xprojb = (__hip_bfloat16*)(ws + 3 * MB8);
    char* wbase = ws + 4 * MB8;
    __hip_bfloat16* wtin   = (__hip_bfloat16*)(wbase);                    // 128KB
    __hip_bfloat16* wtdw2  = (__hip_bfloat16*)(wbase + 131072);           // 128KB
    __hip_bfloat16* wtout  = (__hip_bfloat16*)(wbase + 262144);           // 128KB
    __hip_bfloat16* wtcomb = (__hip_bfloat16*)(wbase + 393216);           // 4096*256*2 = 2MB
    float* bcomb    = (float*)(wbase + 393216 + 2097152);                 // 4096 floats
    float* kws2     = bcomb + NP;                                         // 2048 floats
    float* partials = kws2 + 2048;                                        // 8192 floats

    // 1) merged pre-work: dwconv+xbf | weight transposes | kernel-net (one dispatch)
    pre_kernel<<<NDWB + NPREPB + 1, 256, 0, stream>>>(
        x, dw1_w, dw1_b, w_in, dw2_w, w_out, w_off, w_mask, raw_sigma,
        k0w, k0b, k1w, k1b, k2w, k2b, k3w, k3b, b_off, b_mask,
        xbf, hbf, wtin, wtdw2, wtout, wtcomb, kws2, bcomb);
    // 2) x_proj and x_dw in one dispatch
    gemm_dual_k256<<<dim3(2, 128, 2), 256, 0, stream>>>(xbf, wtin, b_in, xprojb,
                                                        hbf, wtdw2, dw2_b, xdwbf);
    // 3) fused off|mask GEMM + LDS-tile sampling/softmax  (out_pre -> hbf, partials out)
    gemm_fused_sample<<<dim3(NP / 128, MTOT / 128), 256, 0, stream>>>(
        xdwbf, wtcomb, bcomb, xprojb, kws2, hbf, partials);
    // 4) out = out_pre @ w_out + b_out (fp32) + finalize tail block
    gemm_out_k256<<<dim3(2, 129), 256, 0, stream>>>(hbf, wtout, b_out, (float*)d_out,
                                                    partials, (float*)d_out + (size_t)MTOT * CCH);
}

// Round 17
// 120.127 us; speedup vs baseline: 1.0981x; 1.0011x over previous
//
#include <hip/hip_runtime.h>
#include <hip/hip_bf16.h>
#include <hip/hip_fp16.h>
#include <math.h>

#define BB   4
#define LL   4096
#define CCH  256
#define KK   7
#define HIDN 32
#define MTOT (BB * LL)          // 16384 rows
#define NOFF (CCH * KK)         // 1792
#define NP   4096               // padded fused N: col = g*16 + idx (0..6 off, 7 pad, 8..14 mask, 15 pad)
#define NBLK ((NP / 128) * (MTOT / 128))   // 4096 fused blocks
#define NDWB 4096               // dwconv blocks
#define NPREPB 672              // prep blocks (6 tasks x 112)

#define LOG2E  1.4426950408889634f
#define NLOG2E2 (-2.8853900817779268f)   // -2*log2(e)
#define LN2    0.6931471805599453f

typedef __attribute__((ext_vector_type(8))) short short8;
typedef __attribute__((ext_vector_type(4))) short short4v;
typedef __attribute__((ext_vector_type(4))) float f32x4;
typedef __attribute__((ext_vector_type(2))) __fp16 fp16x2;
typedef __attribute__((address_space(1))) void gvoid_t;
typedef __attribute__((address_space(3))) void svoid_t;

__device__ __forceinline__ float siluf(float v) { return v / (1.0f + expf(-v)); }
__device__ __forceinline__ float bf2f(ushort u) { unsigned x = (unsigned)u << 16; return __uint_as_float(x); }
__device__ __forceinline__ float h2f(ushort u) { __half_raw hr; hr.x = u; return __half2float(__half(hr)); }
__device__ __forceinline__ float rcpf(float x) { return __builtin_amdgcn_rcpf(x); }
__device__ __forceinline__ unsigned pkh(float a, float b) {
    union { fp16x2 h; unsigned u; } cv;
    cv.h = __builtin_amdgcn_cvt_pkrtz(a, b);
    return cv.u;
}
__device__ __forceinline__ void compute_env(const float* raw_sigma, float* ev) {
    float sp = log1pf(expf(raw_sigma[0]));
    sp = fminf(fmaxf(sp, 0.05f), 0.5f);
    float sg = fmaxf(sp, 1e-6f);
    float ssum = 0.0f;
    for (int k = 0; k < KK; ++k) {
        float gk = -0.5f + (float)k * (1.0f / 6.0f);
        float d = gk / sg;
        ev[k] = expf(-0.5f * d * d);
        ssum += ev[k];
    }
    ssum = fmaxf(ssum, 1e-8f);
    for (int k = 0; k < KK; ++k) ev[k] /= ssum;
}

// ============ merged pre-work: dwconv+xbf | weight transposes | kernel-net precompute ============
__global__ __launch_bounds__(256) void pre_kernel(
    const float* __restrict__ x, const float* __restrict__ dw1_w, const float* __restrict__ dw1_b,
    const float* __restrict__ w_in, const float* __restrict__ dw2_w, const float* __restrict__ w_out,
    const float* __restrict__ w_off, const float* __restrict__ w_mask,
    const float* __restrict__ raw_sigma,
    const float* __restrict__ k0w, const float* __restrict__ k0b,
    const float* __restrict__ k1w, const float* __restrict__ k1b,
    const float* __restrict__ k2w, const float* __restrict__ k2b,
    const float* __restrict__ k3w, const float* __restrict__ k3b,
    const float* __restrict__ b_off, const float* __restrict__ b_mask,
    __hip_bfloat16* __restrict__ xbf, __hip_bfloat16* __restrict__ hbf,
    __hip_bfloat16* __restrict__ wtin, __hip_bfloat16* __restrict__ wtdw2,
    __hip_bfloat16* __restrict__ wtout, __hip_bfloat16* __restrict__ wtcomb,
    float* __restrict__ kws2, float* __restrict__ bcomb)
{
    const int bid = blockIdx.x;
    const int tid = threadIdx.x;
    __shared__ float t[64][65];
    __shared__ float envs_sh[8];
    __shared__ float h0[KK][HIDN];
    __shared__ float h1[KK][HIDN];
    __shared__ float h2[KK][HIDN];
    __shared__ float flatw[NOFF];

    if (bid < NDWB) {
        size_t base = ((size_t)bid * 256 + tid) * 4;
        int c = (int)(base & (CCH - 1));
        int l = (int)((base >> 8) & (LL - 1));
        float4 xm = *(const float4*)&x[base];
        float4 xl = make_float4(0.f, 0.f, 0.f, 0.f);
        float4 xr = make_float4(0.f, 0.f, 0.f, 0.f);
        if (l > 0)      xl = *(const float4*)&x[base - CCH];
        if (l < LL - 1) xr = *(const float4*)&x[base + CCH];
        float vm[4] = {xm.x, xm.y, xm.z, xm.w};
        float vl[4] = {xl.x, xl.y, xl.z, xl.w};
        float vr[4] = {xr.x, xr.y, xr.z, xr.w};
        ushort xo[4], ho[4];
        #pragma unroll
        for (int j = 0; j < 4; ++j) {
            int cc = c + j;
            float s = vm[j] * dw1_w[cc * 3 + 1] + vl[j] * dw1_w[cc * 3 + 0]
                    + vr[j] * dw1_w[cc * 3 + 2] + dw1_b[cc];
            __hip_bfloat16 hb = __float2bfloat16(siluf(s));
            __hip_bfloat16 xb = __float2bfloat16(vm[j]);
            ho[j] = *(ushort*)&hb;
            xo[j] = *(ushort*)&xb;
        }
        *(short4v*)&xbf[base] = *(short4v*)xo;
        *(short4v*)&hbf[base] = *(short4v*)ho;
        return;
    }
    if (bid < NDWB + NPREPB) {
        const int task = (bid - NDWB) / 112;
        const int bx = (bid - NDWB) % 112;
        if (task == 5) {
            if (bx >= 64) return;
            unsigned u = bx * 256 + tid;
            unsigned row_sel = u >> 5, chunk = u & 31;
            unsigned g = row_sel >> 1, which = row_sel & 1;
            unsigned row = g * 16 + 7 + which * 8;
            short8 z = {};
            *(short8*)((ushort*)wtcomb + (size_t)row * 256 + chunk * 8) = z;
            return;
        }
        const float* src; __hip_bfloat16* dst; int N; int mode = 0;
        switch (task) {
            case 0: src = w_in;  dst = wtin;  N = 256;  break;
            case 1: src = dw2_w; dst = wtdw2; N = 256;  break;
            case 2: src = w_out; dst = wtout; N = 256;  break;
            case 3: src = w_off;  dst = wtcomb; N = NOFF; mode = 1; break;
            default: src = w_mask; dst = wtcomb; N = NOFF; mode = 2; break;
        }
        int ntiles = 4 * (N / 64);
        if (bx >= ntiles) return;
        if (mode == 2 && tid == 0) compute_env(raw_sigma, envs_sh);
        int tk = (bx & 3) * 64;
        int tn = (bx >> 2) * 64;
        #pragma unroll
        for (int i = 0; i < 16; ++i) {
            int e = i * 256 + tid, kk = e >> 6, nn = e & 63;
            t[kk][nn] = src[(size_t)(tk + kk) * N + tn + nn];
        }
        __syncthreads();
        #pragma unroll
        for (int i = 0; i < 16; ++i) {
            int e = i * 256 + tid, nn = e >> 6, kk = e & 63;
            int c = tn + nn;
            float v = t[kk][nn];
            int cp;
            if (mode == 0) cp = c;
            else {
                int g = c / KK, k = c % KK;
                if (mode == 1) { cp = g * 16 + k;     v *= NLOG2E2; }
                else           { cp = g * 16 + 8 + k; v *= envs_sh[k] * LOG2E; }
            }
            dst[(size_t)cp * 256 + tk + kk] = __float2bfloat16(v);
        }
        return;
    }
    {
        int tt = tid;
        if (tt < KK * HIDN) {
            int k = tt / HIDN, j = tt % HIDN;
            float gk = -0.5f + (float)k * (1.0f / 6.0f);
            float v = gk * 30.0f * k0w[j] + k0b[j];
            h0[k][j] = siluf(v);
        }
        __syncthreads();
        if (tt < KK * HIDN) {
            int k = tt / HIDN, j = tt % HIDN;
            float s = k1b[j];
            #pragma unroll
            for (int i = 0; i < HIDN; ++i) s += h0[k][i] * k1w[i * HIDN + j];
            h1[k][j] = siluf(s);
        }
        __syncthreads();
        if (tt < KK * HIDN) {
            int k = tt / HIDN, j = tt % HIDN;
            float s = k2b[j];
            #pragma unroll
            for (int i = 0; i < HIDN; ++i) s += h1[k][i] * k2w[i * HIDN + j];
            h2[k][j] = siluf(s);
        }
        __syncthreads();
        for (int k = 0; k < KK; ++k) {
            float s = k3b[tt];
            #pragma unroll
            for (int i = 0; i < HIDN; ++i) s += h2[k][i] * k3w[i * CCH + tt];
            flatw[k * CCH + tt] = s;
        }
        if (tt == 0) compute_env(raw_sigma, envs_sh);
        __syncthreads();
        #pragma unroll
        for (int k = 0; k < KK; ++k) kws2[tt * 8 + k] = flatw[tt * KK + k];
        kws2[tt * 8 + 7] = 0.0f;
        #pragma unroll
        for (int k = 0; k < KK; ++k) {
            bcomb[tt * 16 + k]     = b_off[tt * KK + k] * NLOG2E2;
            bcomb[tt * 16 + 8 + k] = b_mask[tt * KK + k] * envs_sh[k] * LOG2E;
        }
        bcomb[tt * 16 + 7]  = 0.0f;
        bcomb[tt * 16 + 15] = 0.0f;
    }
}

// ---------------- shared GEMM core (LDS-staged, r11-verified) ----------------
template<int OUTBF>
__device__ __forceinline__ void gemm_core(
    const __hip_bfloat16* __restrict__ A, const __hip_bfloat16* __restrict__ Bt,
    const float* __restrict__ bias, void* __restrict__ C, int N, char* lds,
    int bx, int by)
{
    char* As = lds;
    char* Bs = lds + 16384;
    const int tid = threadIdx.x, lane = tid & 63, w = tid >> 6;
    const int wr = w >> 1, wc = w & 1;
    const size_t m0 = (size_t)by * 128, n0 = (size_t)bx * 128;

    const int srow = w * 32 + (lane >> 3);
    const int sgr  = (lane & 7) ^ ((lane >> 3) & 7);
    const __hip_bfloat16* a_src = A  + (m0 + srow) * 256 + sgr * 8;
    const __hip_bfloat16* b_src = Bt + (n0 + srow) * 256 + sgr * 8;
    char* a_dst = As + (w * 32) * 128;
    char* b_dst = Bs + (w * 32) * 128;

    f32x4 acc[4][4] = {};

    for (int kt = 0; kt < 4; ++kt) {
        const int k0 = kt * 64;
        #pragma unroll
        for (int inst = 0; inst < 4; ++inst) {
            __builtin_amdgcn_global_load_lds((gvoid_t*)(a_src + k0 + (size_t)inst * 8 * 256),
                                             (svoid_t*)(a_dst + inst * 1024), 16, 0, 0);
            __builtin_amdgcn_global_load_lds((gvoid_t*)(b_src + k0 + (size_t)inst * 8 * 256),
                                             (svoid_t*)(b_dst + inst * 1024), 16, 0, 0);
        }
        __syncthreads();
        #pragma unroll
        for (int ks = 0; ks < 2; ++ks) {
            short8 a[4], b[4];
            #pragma unroll
            for (int i = 0; i < 4; ++i) {
                int mr = wr * 64 + i * 16 + (lane & 15);
                int gk = ks * 4 + (lane >> 4);
                a[i] = *(const short8*)(As + mr * 128 + ((gk ^ (mr & 7)) << 4));
                int nr = wc * 64 + i * 16 + (lane & 15);
                b[i] = *(const short8*)(Bs + nr * 128 + ((gk ^ (nr & 7)) << 4));
            }
            #pragma unroll
            for (int i = 0; i < 4; ++i)
                #pragma unroll
                for (int j = 0; j < 4; ++j)
                    acc[i][j] = __builtin_amdgcn_mfma_f32_16x16x32_bf16(a[i], b[j], acc[i][j], 0, 0, 0);
        }
        __syncthreads();
    }
    #pragma unroll
    for (int j = 0; j < 4; ++j) {
        int col = (int)n0 + wc * 64 + j * 16 + (lane & 15);
        float bb = bias[col];
        #pragma unroll
        for (int i = 0; i < 4; ++i) {
            size_t row0 = m0 + wr * 64 + i * 16 + ((lane >> 4) << 2);
            f32x4 v = acc[i][j];
            #pragma unroll
            for (int q = 0; q < 4; ++q) {
                float val = v[q] + bb;
                if (OUTBF) ((__hip_bfloat16*)C)[(row0 + q) * N + col] = __float2bfloat16(val);
                else       ((float*)C)[(row0 + q) * N + col] = val;
            }
        }
    }
}

// dual small GEMM: z=0 -> x_proj, z=1 -> x_dw. XCD-bijective swizzle (256 = 8 x 32).
__global__ __launch_bounds__(256) void gemm_dual_k256(
    const __hip_bfloat16* __restrict__ A0, const __hip_bfloat16* __restrict__ Bt0,
    const float* __restrict__ bias0, __hip_bfloat16* __restrict__ C0,
    const __hip_bfloat16* __restrict__ A1, const __hip_bfloat16* __restrict__ Bt1,
    const float* __restrict__ bias1, __hip_bfloat16* __restrict__ C1)
{
    __shared__ __align__(16) char lds[32768];
    const int flat = blockIdx.y * 2 + blockIdx.x;
    const int wid = ((flat & 7) << 5) | (flat >> 3);
    const int bx = wid & 1, by = wid >> 1;
    if (blockIdx.z == 0) gemm_core<1>(A0, Bt0, bias0, C0, 256, lds, bx, by);
    else                 gemm_core<1>(A1, Bt1, bias1, C1, 256, lds, bx, by);
}

// out GEMM + finalize tail block (by==128). XCD swizzle on the 256 GEMM blocks.
__global__ __launch_bounds__(256) void gemm_out_k256(
    const __hip_bfloat16* __restrict__ A, const __hip_bfloat16* __restrict__ Bt,
    const float* __restrict__ bias, float* __restrict__ C,
    const float* __restrict__ partials, float* __restrict__ out_tail)
{
    __shared__ __align__(16) char lds[32768];
    if (blockIdx.y == 128) {
        if (blockIdx.x != 0) return;
        __shared__ float redr[256], rede[256];
        int t = threadIdx.x;
        float r = 0.0f, e = 0.0f;
        for (int i = t; i < NBLK; i += 256) {
            r += partials[2 * i];
            e += partials[2 * i + 1];
        }
        redr[t] = r; rede[t] = e;
        __syncthreads();
        for (int s = 128; s > 0; s >>= 1) {
            if (t < s) { redr[t] += redr[t + s]; rede[t] += rede[t + s]; }
            __syncthreads();
        }
        if (t == 0) {
            out_tail[0] = redr[0] / 29360128.0f;   // B*L*G*K
            out_tail[1] = rede[0] / 4194304.0f;    // B*L*G
        }
        return;
    }
    const int flat = blockIdx.y * 2 + blockIdx.x;
    const int wid = ((flat & 7) << 5) | (flat >> 3);
    gemm_core<0>(A, Bt, bias, C, 256, lds, wid & 1, wid >> 1);
}

// ---------------- fused off|mask GEMM + LDS-C-tile tanh/gather/softmax epilogue ----------------
// r15 structure exactly; only change: s_setprio(1) around the MFMA cluster (cross-block
// phase diversity on each CU: GEMM-phase waves get issue priority over epilogue waves).
__global__ __launch_bounds__(256) void gemm_fused_sample(
    const __hip_bfloat16* __restrict__ A,      // xdw [16384][256]
    const __hip_bfloat16* __restrict__ Bt,     // wtcomb [4096][256] prescaled
    const float* __restrict__ bcomb,           // [4096] prescaled padded biases
    const __hip_bfloat16* __restrict__ xproj,  // [4][4096][256]
    const float* __restrict__ kws2,            // [256][8] kw, pad k=7 -> 0
    __hip_bfloat16* __restrict__ out_pre,
    float* __restrict__ partials)              // [NBLK][2]
{
    __shared__ __align__(16) char lds[35072];   // 32KB GEMM/Cs + 2.25KB Xs
    char* As = lds;
    char* Bs = lds + 16384;
    const int tid = threadIdx.x, lane = tid & 63, w = tid >> 6;
    const int wr = w >> 1, wc = w & 1;
    // XCD-aware bijective swizzle: each XCD gets 16 contiguous m-panels (A reuse in L2)
    const int flat = blockIdx.y * 32 + blockIdx.x;
    const int wid = ((flat & 7) << 9) | (flat >> 3);
    const int bx = wid & 31, by = wid >> 5;
    const size_t m0 = (size_t)by * 128;
    const int n0 = bx * 128, g0 = bx * 8;
    const int l0 = (int)(m0 & (LL - 1));
    const int bidx = (int)(m0 >> 12);

    // stage Xs (xproj rows l0-5..l0+134, 8 cols) async; completes by first GEMM barrier
    if (tid < 140) {
        int rr = min(max(l0 - 5 + tid, 0), LL - 1);
        const ushort* src = (const ushort*)xproj + ((size_t)bidx * LL + rr) * CCH + g0;
        __builtin_amdgcn_global_load_lds((gvoid_t*)src,
            (svoid_t*)(lds + 32768 + (tid >> 6) * 1024), 16, 0, 0);
    }

    const int srow = w * 32 + (lane >> 3);
    const int sgr  = (lane & 7) ^ ((lane >> 3) & 7);
    const __hip_bfloat16* a_src = A  + (m0 + srow) * 256 + sgr * 8;
    const __hip_bfloat16* b_src = Bt + (size_t)(n0 + srow) * 256 + sgr * 8;
    char* a_dst = As + (w * 32) * 128;
    char* b_dst = Bs + (w * 32) * 128;

    f32x4 acc[4][4] = {};   // acc[j][i], operand-swapped

    for (int kt = 0; kt < 4; ++kt) {
        const int k0 = kt * 64;
        #pragma unroll
        for (int inst = 0; inst < 4; ++inst) {
            __builtin_amdgcn_global_load_lds((gvoid_t*)(a_src + k0 + (size_t)inst * 8 * 256),
                                             (svoid_t*)(a_dst + inst * 1024), 16, 0, 0);
            __builtin_amdgcn_global_load_lds((gvoid_t*)(b_src + k0 + (size_t)inst * 8 * 256),
                                             (svoid_t*)(b_dst + inst * 1024), 16, 0, 0);
        }
        __syncthreads();
        #pragma unroll
        for (int ks = 0; ks < 2; ++ks) {
            short8 a[4], b[4];
            #pragma unroll
            for (int i = 0; i < 4; ++i) {
                int mr = wr * 64 + i * 16 + (lane & 15);
                int gk = ks * 4 + (lane >> 4);
                a[i] = *(const short8*)(As + mr * 128 + ((gk ^ (mr & 7)) << 4));
                int nr = wc * 64 + i * 16 + (lane & 15);
                b[i] = *(const short8*)(Bs + nr * 128 + ((gk ^ (nr & 7)) << 4));
            }
            __builtin_amdgcn_s_setprio(1);
            #pragma unroll
            for (int i = 0; i < 4; ++i)
                #pragma unroll
                for (int j = 0; j < 4; ++j)
                    acc[j][i] = __builtin_amdgcn_mfma_f32_16x16x32_bf16(b[j], a[i], acc[j][i], 0, 0, 0);
            __builtin_amdgcn_s_setprio(0);
        }
        __syncthreads();
    }

    // ---- epilogue 1: bias + fp16 pack, b64 store into swizzled Cs (reuses As/Bs) ----
    {
        const int rl = lane & 15, grp = lane >> 4;
        #pragma unroll
        for (int j = 0; j < 4; ++j) {
            float4 bi = *(const float4*)&bcomb[n0 + wc * 64 + j * 16 + grp * 4];
            const int gran = wc * 8 + j * 2 + (grp >> 1);
            #pragma unroll
            for (int i = 0; i < 4; ++i) {
                f32x4 v = acc[j][i];
                uint2 pk;
                pk.x = pkh(v[0] + bi.x, v[1] + bi.y);
                pk.y = pkh(v[2] + bi.z, v[3] + bi.w);
                int row = wr * 64 + i * 16 + rl;
                int addr = row * 256 + ((gran ^ rl) << 4) + (grp & 1) * 8;
                *(uint2*)(lds + addr) = pk;
            }
        }
    }
    __syncthreads();

    // ---- epilogue 2: 4 points/thread (softmax without max-subtraction) ----
    const ushort* XsL = (const ushort*)(lds + 32768);
    const int gg = tid & 7, rb = tid >> 3;   // rb 0..31
    float kwv[KK];
    {
        const float* kp = &kws2[(size_t)(g0 + gg) * 8];
        float4 ka = *(const float4*)kp;
        float4 kb = *(const float4*)(kp + 4);
        kwv[0] = ka.x; kwv[1] = ka.y; kwv[2] = ka.z; kwv[3] = ka.w;
        kwv[4] = kb.x; kwv[5] = kb.y; kwv[6] = kb.z;
    }
    float reg_acc = 0.0f, ent_acc = 0.0f;
    #pragma unroll
    for (int pp = 0; pp < 4; ++pp) {
        const int r = rb + 32 * pp;
        short8 ca = *(const short8*)(lds + r * 256 + (((2 * gg) ^ (r & 15)) << 4));
        short8 cb = *(const short8*)(lds + r * 256 + (((2 * gg + 1) ^ (r & 15)) << 4));
        const int l = l0 + r;
        float es = 0.0f, tacc = 0.0f, o = 0.0f;
        #pragma unroll
        for (int k = 0; k < KK; ++k) {
            float mvk = h2f((ushort)cb[k]);        // env-scaled logit; small, no max-sub
            float e = exp2f(mvk);
            es += e; tacc += e * mvk;
            float zp = fminf(h2f((ushort)ca[k]), 80.f);   // = -2z*log2e (one-sided clamp)
            float ee = exp2f(zp);                          // = exp(-2z)
            float ov = 2.0f * (1.0f - ee) * rcpf(1.0f + ee);   // = 2*tanh(z)
            reg_acc += ov * ov;
            float p = fminf(fmaxf((float)(l + k - 3) + ov, 0.0f), 4095.0f);
            int pf = (int)p;
            float wcf = p - (float)pf;
            int ix = pf - (l0 - 5);
            float sv = bf2f(XsL[ix * 8 + gg]) * (1.0f - wcf) + bf2f(XsL[ix * 8 + 8 + gg]) * wcf;
            o += sv * kwv[k] * e;
        }
        float inv = rcpf(es);
        ent_acc += tacc * inv - __log2f(es);
        out_pre[(m0 + r) * CCH + g0 + gg] = __float2bfloat16(o * inv);
    }

    // wave butterfly, then per-block partial via LDS (no atomics)
    #pragma unroll
    for (int d = 1; d < 64; d <<= 1) {
        reg_acc += __shfl_xor(reg_acc, d);
        ent_acc += __shfl_xor(ent_acc, d);
    }
    __syncthreads();                       // all Cs/Xs reads complete before LDS reuse
    float* redv = (float*)lds;
    if (lane == 0) { redv[w] = reg_acc; redv[4 + w] = ent_acc; }
    __syncthreads();
    if (tid == 0) {
        float r2 = redv[0] + redv[1] + redv[2] + redv[3];
        float e2 = redv[4] + redv[5] + redv[6] + redv[7];
        partials[wid * 2]     = r2;
        partials[wid * 2 + 1] = e2 * LN2;
    }
}

extern "C" void kernel_launch(void* const* d_in, const int* in_sizes, int n_in,
                              void* d_out, int out_size, void* d_ws, size_t ws_size,
                              hipStream_t stream)
{
    const float* x         = (const float*)d_in[0];
    const float* raw_sigma = (const float*)d_in[1];
    const float* w_in      = (const float*)d_in[2];
    const float* b_in      = (const float*)d_in[3];
    const float* w_out     = (const float*)d_in[4];
    const float* b_out     = (const float*)d_in[5];
    const float* dw1_w     = (const float*)d_in[6];
    const float* dw1_b     = (const float*)d_in[7];
    const float* dw2_w     = (const float*)d_in[8];
    const float* dw2_b     = (const float*)d_in[9];
    const float* w_off     = (const float*)d_in[10];
    const float* b_off     = (const float*)d_in[11];
    const float* w_mask    = (const float*)d_in[12];
    const float* b_mask    = (const float*)d_in[13];
    const float* k0w       = (const float*)d_in[14];
    const float* k0b       = (const float*)d_in[15];
    const float* k1w       = (const float*)d_in[16];
    const float* k1b       = (const float*)d_in[17];
    const float* k2w       = (const float*)d_in[18];
    const float* k2b       = (const float*)d_in[19];
    const float* k3w       = (const float*)d_in[20];
    const float* k3b       = (const float*)d_in[21];

    char* ws = (char*)d_ws;
    const size_t MB8 = (size_t)8 * 1024 * 1024;
    __hip_bfloat16* xbf    = (__hip_bfloat16*)(ws + 0);
    __hip_bfloat16* hbf    = (__hip_bfloat16*)(ws + MB8);        // h, reused as out_pre
    __hip_bfloat16* xdwbf  = (__hip_bfloat16*)(ws + 2 * MB8);
    __hip_bfloat16* xprojb = (__hip_bfloat16*)(ws + 3 * MB8);
    char* wbase = ws + 4 * MB8;
    __hip_bfloat16* wtin   = (__hip_bfloat16*)(wbase);                    // 128KB
    __hip_bfloat16* wtdw2  = (__hip_bfloat16*)(wbase + 131072);           // 128KB
    __hip_bfloat16* wtout  = (__hip_bfloat16*)(wbase + 262144);           // 128KB
    __hip_bfloat16* wtcomb = (__hip_bfloat16*)(wbase + 393216);           // 4096*256*2 = 2MB
    float* bcomb    = (float*)(wbase + 393216 + 2097152);                 // 4096 floats
    float* kws2     = bcomb + NP;                                         // 2048 floats
    float* partials = kws2 + 2048;                                        // 8192 floats

    // 1) merged pre-work: dwconv+xbf | weight transposes | kernel-net (one dispatch)
    pre_kernel<<<NDWB + NPREPB + 1, 256, 0, stream>>>(
        x, dw1_w, dw1_b, w_in, dw2_w, w_out, w_off, w_mask, raw_sigma,
        k0w, k0b, k1w, k1b, k2w, k2b, k3w, k3b, b_off, b_mask,
        xbf, hbf, wtin, wtdw2, wtout, wtcomb, kws2, bcomb);
    // 2) x_proj and x_dw in one dispatch
    gemm_dual_k256<<<dim3(2, 128, 2), 256, 0, stream>>>(xbf, wtin, b_in, xprojb,
                                                        hbf, wtdw2, dw2_b, xdwbf);
    // 3) fused off|mask GEMM + LDS-tile sampling/softmax  (out_pre -> hbf, partials out)
    gemm_fused_sample<<<dim3(NP / 128, MTOT / 128), 256, 0, stream>>>(
        xdwbf, wtcomb, bcomb, xprojb, kws2, hbf, partials);
    // 4) out = out_pre @ w_out + b_out (fp32) + finalize tail block
    gemm_out_k256<<<dim3(2, 129), 256, 0, stream>>>(hbf, wtout, b_out, (float*)d_out,
                                                    partials, (float*)d_out + (size_t)MTOT * CCH);
}